// Round 12
// baseline (2461.881 us; speedup 1.0000x reference)
//
#include <hip/hip_runtime.h>

#define DEVFN __device__ __forceinline__

static inline int ceil_div(int a, int b) { return (a + b - 1) / b; }

typedef __attribute__((ext_vector_type(8))) short         bf16x8;  // 8 bf16 = 4 VGPR
typedef __attribute__((ext_vector_type(4))) float         f32x4;
typedef __attribute__((ext_vector_type(8))) unsigned short u16x8;

DEVFN unsigned short f2bf(float x) {           // RNE float->bf16 (finite inputs)
    unsigned u = __float_as_uint(x);
    unsigned r = ((u >> 16) & 1u) + 0x7fffu;
    return (unsigned short)((u + r) >> 16);
}
DEVFN float bf2f(unsigned short h) { return __uint_as_float(((unsigned)h) << 16); }

// ---------------------------------------------------------------------------
// DPP-based 64-lane max reduction step for a packed double key.
// ---------------------------------------------------------------------------
template<int CTRL>
DEVFN double dpp_max_step(double v)
{
    int lo = __double2loint(v), hi = __double2hiint(v);
    int tlo = __builtin_amdgcn_update_dpp(lo, lo, CTRL, 0xF, 0xF, false);
    int thi = __builtin_amdgcn_update_dpp(hi, hi, CTRL, 0xF, 0xF, false);
    return fmax(v, __hiloint2double(thi, tlo));
}

// ---------------------------------------------------------------------------
// Farthest point sampling — SINGLE WAVE per batch, packed-key argmax with
// 6-step DPP max reduce (unchanged; 202 µs @ N=1024).
// ---------------------------------------------------------------------------
template<int N>
__global__ __launch_bounds__(64) void fps_kernel(const float* __restrict__ xyz, int M,
                                                 int* __restrict__ out_idx,
                                                 float* __restrict__ nxout)
{
    constexpr int PPL = N / 64;
    int b = blockIdx.x, lane = threadIdx.x;
    __shared__ float4 sp[N];
    const float* p = xyz + (size_t)b * N * 3;
    float px[PPL], py[PPL], pz[PPL], dd[PPL];
    unsigned lo[PPL];
    #pragma unroll
    for (int j = 0; j < PPL; ++j) {
        int idx = lane + 64 * j;
        px[j] = p[idx*3+0]; py[j] = p[idx*3+1]; pz[j] = p[idx*3+2];
        sp[idx] = make_float4(px[j], py[j], pz[j], 0.f);
        dd[j] = 1e10f;
        lo[j] = ~(unsigned)idx;
    }
    __syncthreads();
    int far = 0;
    for (int s = 0; s < M; ++s) {
        float4 c4 = sp[far];
        if (lane == 0) {
            out_idx[(size_t)b*M + s] = far;
            nxout[((size_t)b*M + s)*3 + 0] = c4.x;
            nxout[((size_t)b*M + s)*3 + 1] = c4.y;
            nxout[((size_t)b*M + s)*3 + 2] = c4.z;
        }
        double cand[PPL];
        #pragma unroll
        for (int j = 0; j < PPL; ++j) {
            float dx = __fsub_rn(px[j], c4.x);
            float dy = __fsub_rn(py[j], c4.y);
            float dz = __fsub_rn(pz[j], c4.z);
            float d  = __fadd_rn(__fadd_rn(__fmul_rn(dx,dx), __fmul_rn(dy,dy)),
                                 __fmul_rn(dz,dz));
            float nd = fminf(dd[j], d);
            dd[j] = nd;
            cand[j] = __hiloint2double(__float_as_int(nd), (int)lo[j]);
        }
        #pragma unroll
        for (int st = PPL/2; st > 0; st >>= 1)
            #pragma unroll
            for (int j = 0; j < PPL; ++j)
                if (j < st) cand[j] = fmax(cand[j], cand[j + st]);
        double v = cand[0];
        v = dpp_max_step<0xB1>(v);
        v = dpp_max_step<0x4E>(v);
        v = dpp_max_step<0x124>(v);
        v = dpp_max_step<0x128>(v);
        v = dpp_max_step<0x142>(v);
        v = dpp_max_step<0x143>(v);
        int wlo = __builtin_amdgcn_readlane(__double2loint(v), 63);
        far = (int)(~(unsigned)wlo);
    }
}

// ---------------------------------------------------------------------------
// Ball query (unchanged).
// ---------------------------------------------------------------------------
__global__ void ballquery_kernel(const float* __restrict__ xyz,
                                 const float* __restrict__ new_xyz,
                                 int* __restrict__ gi,
                                 int B, int N, int M, int K, float r2)
{
    int t = blockIdx.x * blockDim.x + threadIdx.x;
    if (t >= B * M) return;
    int b = t / M;
    const float* p = xyz + (size_t)b * N * 3;
    float cx = new_xyz[t*3+0], cy = new_xyz[t*3+1], cz = new_xyz[t*3+2];
    int* out = gi + (size_t)t * K;
    int cnt = 0, first = 0;
    bool havefirst = false;
    for (int i = 0; i < N; ++i) {
        float dx = __fsub_rn(p[i*3+0], cx);
        float dy = __fsub_rn(p[i*3+1], cy);
        float dz = __fsub_rn(p[i*3+2], cz);
        float d  = __fadd_rn(__fadd_rn(__fmul_rn(dx,dx), __fmul_rn(dy,dy)),
                             __fmul_rn(dz,dz));
        if (d <= r2) {
            if (!havefirst) { first = i; havefirst = true; }
            out[cnt++] = i;
            if (cnt == K) break;
        }
    }
    for (; cnt < K; ++cnt) out[cnt] = first;
}

DEVFN float f4_elem(const float4& v, int u) {
    return u == 0 ? v.x : u == 1 ? v.y : u == 2 ? v.z : v.w;
}

// ---------------------------------------------------------------------------
// Weight split+transpose prep: w [CI][CO] fp32 -> wh/wl [CO][CI] bf16 pair.
// ---------------------------------------------------------------------------
__global__ void wsplit_kernel(const float* __restrict__ w,
                              unsigned short* __restrict__ wh,
                              unsigned short* __restrict__ wl, int CI, int CO)
{
    int t = blockIdx.x * 256 + threadIdx.x;
    if (t >= CI * CO) return;
    int co = t / CI, ci = t % CI;
    float v = w[(size_t)ci * CO + co];
    unsigned short h = f2bf(v);
    wh[t] = h;
    wl[t] = f2bf(v - bf2f(h));
}

// Elementwise fp32 -> split bf16 pair (same layout).
__global__ void asplit_kernel(const float* __restrict__ a,
                              unsigned short* __restrict__ ah,
                              unsigned short* __restrict__ al, int n)
{
    int t = blockIdx.x * 256 + threadIdx.x;
    if (t >= n) return;
    float v = a[t];
    unsigned short h = f2bf(v);
    ah[t] = h;
    al[t] = f2bf(v - bf2f(h));
}

// ---------------------------------------------------------------------------
// SA layer 1 (fused gather + centering), fp32 VALU, RPL=1 (R10-winning form),
// now writing ROW-MAJOR split-bf16 activations for the MFMA layers.
// ---------------------------------------------------------------------------
template<int CF, int CO, int KPTS>
__global__ __launch_bounds__(256) void sa_l1_kernel(
    const float* __restrict__ xyz, const float* __restrict__ feats,
    const float* __restrict__ new_xyz, const int* __restrict__ gi,
    const float* __restrict__ w, const float* __restrict__ bias,
    unsigned short* __restrict__ oh, unsigned short* __restrict__ ol,
    int N, int M, int row0)
{
    constexpr int WCH = CO / 4;
    const int lane = threadIdx.x & 63;
    const int wv   = __builtin_amdgcn_readfirstlane(threadIdx.x >> 6);
    const int rl   = blockIdx.x * 64 + lane;
    const int row  = row0 + rl;
    const int cent = row / KPTS;
    const int b    = cent / M;
    const int idx  = gi[row];
    const float* pp  = xyz + ((size_t)b*N + idx)*3;
    const float* cc3 = new_xyz + (size_t)cent*3;
    float a0 = __fsub_rn(pp[0], cc3[0]);
    float a1 = __fsub_rn(pp[1], cc3[1]);
    float a2 = __fsub_rn(pp[2], cc3[2]);
    const float* frow = feats + ((size_t)b*N + idx)*CF;
    const float* wcol = w + wv*WCH;
    const float* bcol = bias + wv*WCH;
    float acc[WCH];
    #pragma unroll
    for (int j = 0; j < WCH; ++j) acc[j] = bcol[j];
    #pragma unroll
    for (int j = 0; j < WCH; ++j) acc[j] += a0 * wcol[0*CO + j];
    #pragma unroll
    for (int j = 0; j < WCH; ++j) acc[j] += a1 * wcol[1*CO + j];
    #pragma unroll
    for (int j = 0; j < WCH; ++j) acc[j] += a2 * wcol[2*CO + j];
    constexpr int CF4 = CF & ~3;
    #pragma unroll 2
    for (int cc = 0; cc < CF4; cc += 4) {
        float4 a4 = *(const float4*)(frow + cc);
        #pragma unroll
        for (int u = 0; u < 4; ++u) {
            float a = f4_elem(a4, u);
            #pragma unroll
            for (int j = 0; j < WCH; ++j)
                acc[j] += a * wcol[(size_t)(3 + cc + u)*CO + j];
        }
    }
    #pragma unroll
    for (int f = CF4; f < CF; ++f) {
        float a = frow[f];
        #pragma unroll
        for (int j = 0; j < WCH; ++j)
            acc[j] += a * wcol[(size_t)(3 + f)*CO + j];
    }
    #pragma unroll
    for (int j8 = 0; j8 < WCH; j8 += 8) {
        u16x8 hv, lv;
        #pragma unroll
        for (int u = 0; u < 8; ++u) {
            float v = fmaxf(acc[j8+u], 0.f);
            unsigned short h = f2bf(v);
            hv[u] = (unsigned short)h;
            lv[u] = f2bf(v - bf2f(h));
        }
        size_t o = (size_t)rl*CO + wv*WCH + j8;
        *(u16x8*)(&oh[o]) = hv;
        *(u16x8*)(&ol[o]) = lv;
    }
}

// ---------------------------------------------------------------------------
// MFMA layer: act row-major split bf16 [R][CI] x weights [CO][CI] split bf16
// -> bias+relu. Two-split product: Ah*Bh + Ah*Bl + Al*Bh (fp32 accum).
// Block = 256 thr = 4 waves, 64 rows/block; wave owns 16 rows x all CO.
// Fragment layout (v_mfma_f32_16x16x32_bf16):
//   A: a[j] = A[lane&15][(lane>>4)*8 + j]     B: b[j] = B[(lane>>4)*8+j][lane&15]
//   D: d[r] = D[(lane>>4)*4 + r][lane&15]     (verified C/D mapping)
// OUTMODE: 0 = split-bf16 out, 1 = fp32 row-major out, 2 = maxpool(KPTS)->fp32
// ---------------------------------------------------------------------------
template<int CI, int CO, int KPTS, int OUTMODE>
__global__ __launch_bounds__(256) void mfma_layer_kernel(
    const unsigned short* __restrict__ ah, const unsigned short* __restrict__ al,
    const unsigned short* __restrict__ wh, const unsigned short* __restrict__ wl,
    const float* __restrict__ bias,
    unsigned short* __restrict__ oh, unsigned short* __restrict__ ol,
    float* __restrict__ ofp, int rowbase)
{
    constexpr int NT = CO / 16;
    constexpr int KT = CI / 32;
    constexpr bool PRE = (KT <= 4);
    __shared__ float partial[4][OUTMODE == 2 ? CO : 1];
    const int wid  = threadIdx.x >> 6;
    const int lane = threadIdx.x & 63;
    const int m    = lane & 15;
    const int kg   = lane >> 4;
    const int row0 = blockIdx.x * 64 + wid * 16;
    const unsigned short* arh = ah + (size_t)(row0 + m) * CI + kg * 8;
    const unsigned short* arl = al + (size_t)(row0 + m) * CI + kg * 8;
    bf16x8 Ah[PRE ? KT : 1], Al[PRE ? KT : 1];
    if constexpr (PRE) {
        #pragma unroll
        for (int kt = 0; kt < KT; ++kt) {
            Ah[kt] = *(const bf16x8*)(arh + kt*32);
            Al[kt] = *(const bf16x8*)(arl + kt*32);
        }
    }
    for (int nt = 0; nt < NT; ++nt) {
        f32x4 acc = {0.f, 0.f, 0.f, 0.f};
        const unsigned short* wbh = wh + (size_t)(nt*16 + m) * CI + kg * 8;
        const unsigned short* wbl = wl + (size_t)(nt*16 + m) * CI + kg * 8;
        #pragma unroll 4
        for (int kt = 0; kt < KT; ++kt) {
            bf16x8 Bh = *(const bf16x8*)(wbh + kt*32);
            bf16x8 Bl = *(const bf16x8*)(wbl + kt*32);
            bf16x8 a_h, a_l;
            if constexpr (PRE) { a_h = Ah[kt]; a_l = Al[kt]; }
            else {
                a_h = *(const bf16x8*)(arh + kt*32);
                a_l = *(const bf16x8*)(arl + kt*32);
            }
            acc = __builtin_amdgcn_mfma_f32_16x16x32_bf16(a_h, Bh, acc, 0, 0, 0);
            acc = __builtin_amdgcn_mfma_f32_16x16x32_bf16(a_h, Bl, acc, 0, 0, 0);
            acc = __builtin_amdgcn_mfma_f32_16x16x32_bf16(a_l, Bh, acc, 0, 0, 0);
        }
        int dcol = nt*16 + m;
        float bv = bias[dcol];
        float v[4];
        #pragma unroll
        for (int r = 0; r < 4; ++r) v[r] = fmaxf(acc[r] + bv, 0.f);
        if constexpr (OUTMODE == 0) {
            #pragma unroll
            for (int r = 0; r < 4; ++r) {
                size_t o = (size_t)(row0 + kg*4 + r) * CO + dcol;
                unsigned short h = f2bf(v[r]);
                oh[o] = h;
                ol[o] = f2bf(v[r] - bf2f(h));
            }
        } else if constexpr (OUTMODE == 1) {
            #pragma unroll
            for (int r = 0; r < 4; ++r)
                ofp[(size_t)(row0 + kg*4 + r) * CO + dcol] = v[r];
        } else {
            float mx = fmaxf(fmaxf(v[0], v[1]), fmaxf(v[2], v[3]));
            mx = fmaxf(mx, __shfl_xor(mx, 16));
            mx = fmaxf(mx, __shfl_xor(mx, 32));
            if (lane < 16) partial[wid][dcol] = mx;
        }
    }
    if constexpr (OUTMODE == 2) {
        __syncthreads();
        for (int c = threadIdx.x; c < CO; c += 256) {
            if constexpr (KPTS == 64) {
                float mx = fmaxf(fmaxf(partial[0][c], partial[1][c]),
                                 fmaxf(partial[2][c], partial[3][c]));
                int cent = (rowbase + blockIdx.x*64) / 64;
                ofp[(size_t)cent*CO + c] = mx;
            } else {               // KPTS == 32: block covers 2 centroids
                int cent0 = (rowbase + blockIdx.x*64) / 32;
                ofp[(size_t)cent0*CO + c]       = fmaxf(partial[0][c], partial[1][c]);
                ofp[(size_t)(cent0+1)*CO + c]   = fmaxf(partial[2][c], partial[3][c]);
            }
        }
    }
}

// ---------------------------------------------------------------------------
// concat [R,3] ++ [R,CF] -> [R,3+CF]
// ---------------------------------------------------------------------------
__global__ void concat_kernel(const float* __restrict__ a, const float* __restrict__ f,
                              float* __restrict__ out, int R, int CF)
{
    int C = CF + 3;
    int t = blockIdx.x * blockDim.x + threadIdx.x;
    if (t >= R * C) return;
    int r = t / C, c = t % C;
    out[t] = (c < 3) ? a[r*3 + c] : f[(size_t)r * CF + (c - 3)];
}

// ---------------------------------------------------------------------------
// Tiled fp32 GEMM, 64x64 tile / 4x4 micro (K=259 layer + FC head).
// ---------------------------------------------------------------------------
template<int RELU, int HASB>
__global__ __launch_bounds__(256) void gemm_kernel(
    const float* __restrict__ A, const float* __restrict__ W,
    const float* __restrict__ bias, float* __restrict__ Cc,
    int Mr, int Nc, int Kd)
{
    __shared__ float As[64][17];
    __shared__ float Ws[16][65];
    int tx = threadIdx.x % 16;
    int ty = threadIdx.x / 16;
    int row0 = blockIdx.y * 64;
    int col0 = blockIdx.x * 64;
    float acc[4][4] = {};
    for (int k0 = 0; k0 < Kd; k0 += 16) {
        for (int t = threadIdx.x; t < 64*16; t += 256) {
            int r = t >> 4, kk = t & 15;
            int gr = row0 + r, gk = k0 + kk;
            As[r][kk] = (gr < Mr && gk < Kd) ? A[(size_t)gr * Kd + gk] : 0.f;
        }
        for (int t = threadIdx.x; t < 16*64; t += 256) {
            int kk = t >> 6, c = t & 63;
            int gk = k0 + kk, gc = col0 + c;
            Ws[kk][c] = (gk < Kd && gc < Nc) ? W[(size_t)gk * Nc + gc] : 0.f;
        }
        __syncthreads();
        #pragma unroll
        for (int kk = 0; kk < 16; ++kk) {
            float av[4], wv[4];
            #pragma unroll
            for (int i = 0; i < 4; i++) av[i] = As[ty*4+i][kk];
            #pragma unroll
            for (int j = 0; j < 4; j++) wv[j] = Ws[kk][tx*4+j];
            #pragma unroll
            for (int i = 0; i < 4; i++)
                #pragma unroll
                for (int j = 0; j < 4; j++)
                    acc[i][j] += av[i] * wv[j];
        }
        __syncthreads();
    }
    #pragma unroll
    for (int i = 0; i < 4; i++) {
        int gr = row0 + ty*4 + i;
        if (gr >= Mr) continue;
        #pragma unroll
        for (int j = 0; j < 4; j++) {
            int gc = col0 + tx*4 + j;
            if (gc >= Nc) continue;
            float v = acc[i][j];
            if (HASB) v += bias[gc];
            if (RELU) v = fmaxf(v, 0.f);
            Cc[(size_t)gr * Nc + gc] = v;
        }
    }
}

// ---------------------------------------------------------------------------
// Max over P points: in [B,P,C] -> out [B,C]
// ---------------------------------------------------------------------------
__global__ void rowmax_kernel(const float* __restrict__ in, float* __restrict__ out,
                              int B, int P, int C)
{
    int t = blockIdx.x * blockDim.x + threadIdx.x;
    if (t >= B * C) return;
    int b = t / C, c = t % C;
    const float* p = in + (size_t)b * P * C + c;
    float mx = p[0];
    for (int i = 1; i < P; ++i) mx = fmaxf(mx, p[(size_t)i * C]);
    out[t] = mx;
}

// ---------------------------------------------------------------------------
extern "C" void kernel_launch(void* const* d_in, const int* in_sizes, int n_in,
                              void* d_out, int out_size, void* d_ws, size_t ws_size,
                              hipStream_t stream)
{
    const float* xyz    = (const float*)d_in[0];
    const float* points = (const float*)d_in[1];
    const float* w1a = (const float*)d_in[2];  const float* b1a = (const float*)d_in[3];
    const float* w1b = (const float*)d_in[4];  const float* b1b = (const float*)d_in[5];
    const float* w1c = (const float*)d_in[6];  const float* b1c = (const float*)d_in[7];
    const float* w2a = (const float*)d_in[8];  const float* b2a = (const float*)d_in[9];
    const float* w2b = (const float*)d_in[10]; const float* b2b = (const float*)d_in[11];
    const float* w2c = (const float*)d_in[12]; const float* b2c = (const float*)d_in[13];
    const float* w3a = (const float*)d_in[14]; const float* b3a = (const float*)d_in[15];
    const float* w3b = (const float*)d_in[16]; const float* b3b = (const float*)d_in[17];
    const float* w3c = (const float*)d_in[18]; const float* b3c = (const float*)d_in[19];
    const float* lin1 = (const float*)d_in[20];
    const float* lin2 = (const float*)d_in[21];
    const float* clsw = (const float*)d_in[22];
    const float* clsb = (const float*)d_in[23];

    char* ws = (char*)d_ws;
    size_t off = 0;
    auto alloc = [&](size_t bytes) -> void* {
        void* p = ws + off;
        off += (bytes + 255) & ~(size_t)255;
        return p;
    };
    int*   fps1 = (int*)  alloc((size_t)32*512*4);
    float* nx1  = (float*)alloc((size_t)32*512*3*4);
    int*   gi1  = (int*)  alloc((size_t)32*512*32*4);
    float* f1   = (float*)alloc((size_t)32*512*128*4);
    int*   fps2 = (int*)  alloc((size_t)32*128*4);
    float* nx2  = (float*)alloc((size_t)32*128*3*4);
    int*   gi2  = (int*)  alloc((size_t)32*128*64*4);
    float* f2   = (float*)alloc((size_t)32*128*256*4);
    float* g3   = (float*)alloc((size_t)4096*259*4);
    float* h3a  = (float*)alloc((size_t)4096*256*4);
    float* h3c  = (float*)alloc((size_t)4096*1024*4);
    float* f3   = (float*)alloc((size_t)32*1024*4);
    float* fc1  = (float*)alloc((size_t)32*512*4);
    float* fc2  = (float*)alloc((size_t)32*256*4);

    typedef unsigned short us;
    // split weights (transposed [CO][CI], bf16 hi/lo)
    us* w1bh = (us*)alloc(64*64*2);     us* w1bl = (us*)alloc(64*64*2);
    us* w1ch = (us*)alloc(128*64*2);    us* w1cl = (us*)alloc(128*64*2);
    us* w2bh = (us*)alloc(128*128*2);   us* w2bl = (us*)alloc(128*128*2);
    us* w2ch = (us*)alloc(256*128*2);   us* w2cl = (us*)alloc(256*128*2);
    us* w3bh = (us*)alloc(512*256*2);   us* w3bl = (us*)alloc(512*256*2);
    us* w3ch = (us*)alloc(1024*512*2);  us* w3cl = (us*)alloc(1024*512*2);
    // split SA3 activations
    us* h3aH = (us*)alloc((size_t)4096*256*2);  us* h3aL = (us*)alloc((size_t)4096*256*2);
    us* h3bH = (us*)alloc((size_t)4096*512*2);  us* h3bL = (us*)alloc((size_t)4096*512*2);

    // big split activation ping-pong buffers (hi/lo per side)
    size_t avail = (ws_size > off + 1024) ? (ws_size - off - 1024) : 0;
    size_t bufcap = avail / 4;
    if (bufcap > (size_t)67200000) bufcap = 67200000;   // 524288 rows x 64ch x 2B
    us* Ah = (us*)alloc(bufcap); us* Al = (us*)alloc(bufcap);
    us* Bh = (us*)alloc(bufcap); us* Bl = (us*)alloc(bufcap);

    // ---- weight prep (independent of data flow)
    auto wsp = [&](const float* w, int CI, int CO, us* wh, us* wl) {
        wsplit_kernel<<<ceil_div(CI*CO, 256), 256, 0, stream>>>(w, wh, wl, CI, CO);
    };
    wsp(w1b, 64, 64,  w1bh, w1bl);
    wsp(w1c, 64, 128, w1ch, w1cl);
    wsp(w2b, 128, 128, w2bh, w2bl);
    wsp(w2c, 128, 256, w2ch, w2cl);
    wsp(w3b, 256, 512, w3bh, w3bl);
    wsp(w3c, 512, 1024, w3ch, w3cl);

    // ---- SA1: N=1024 -> M=512, r=0.2, K=32, MLP 6->64->64->128
    fps_kernel<1024><<<32, 64, 0, stream>>>(xyz, 512, fps1, nx1);
    ballquery_kernel<<<ceil_div(32*512, 256), 256, 0, stream>>>(
        xyz, nx1, gi1, 32, 1024, 512, 32, (float)(0.2*0.2));
    {
        const int rows = 32*512*32;                     // 524288
        int ch = (int)((bufcap / (64*2)) & ~(size_t)255);
        if (ch > rows) ch = rows;
        if (ch < 256) ch = 256;
        for (int r0 = 0; r0 < rows; r0 += ch) {
            int rc = rows - r0 < ch ? rows - r0 : ch;
            sa_l1_kernel<3, 64, 32><<<rc/64, 256, 0, stream>>>(
                xyz, points, nx1, gi1, w1a, b1a, Ah, Al, 1024, 512, r0);
            mfma_layer_kernel<64, 64, 0, 0><<<rc/64, 256, 0, stream>>>(
                Ah, Al, w1bh, w1bl, b1b, Bh, Bl, nullptr, 0);
            mfma_layer_kernel<64, 128, 32, 2><<<rc/64, 256, 0, stream>>>(
                Bh, Bl, w1ch, w1cl, b1c, nullptr, nullptr, f1, r0);
        }
    }

    // ---- SA2: N=512 -> M=128, r=0.4, K=64, MLP 131->128->128->256
    fps_kernel<512><<<32, 64, 0, stream>>>(nx1, 128, fps2, nx2);
    ballquery_kernel<<<ceil_div(32*128, 256), 256, 0, stream>>>(
        nx1, nx2, gi2, 32, 512, 128, 64, (float)(0.4*0.4));
    {
        const int rows = 32*128*64;                     // 262144
        int ch = (int)((bufcap / (128*2)) & ~(size_t)255);
        if (ch > rows) ch = rows;
        if (ch < 256) ch = 256;
        for (int r0 = 0; r0 < rows; r0 += ch) {
            int rc = rows - r0 < ch ? rows - r0 : ch;
            sa_l1_kernel<128, 128, 64><<<rc/64, 256, 0, stream>>>(
                nx1, f1, nx2, gi2, w2a, b2a, Ah, Al, 512, 128, r0);
            mfma_layer_kernel<128, 128, 0, 0><<<rc/64, 256, 0, stream>>>(
                Ah, Al, w2bh, w2bl, b2b, Bh, Bl, nullptr, 0);
            mfma_layer_kernel<128, 256, 64, 2><<<rc/64, 256, 0, stream>>>(
                Bh, Bl, w2ch, w2cl, b2c, nullptr, nullptr, f2, r0);
        }
    }

    // ---- SA3 (group_all): concat [4096,259] -> 259->256 (fp32 gemm) ->
    //      256->512 (mfma) -> 512->1024 (mfma) -> max over 128
    concat_kernel<<<ceil_div(4096*259, 256), 256, 0, stream>>>(nx2, f2, g3, 4096, 256);
    {
        dim3 g(ceil_div(256, 64), ceil_div(4096, 64));
        gemm_kernel<1,1><<<g, 256, 0, stream>>>(g3, w3a, b3a, h3a, 4096, 256, 259);
    }
    asplit_kernel<<<ceil_div(4096*256, 256), 256, 0, stream>>>(h3a, h3aH, h3aL, 4096*256);
    mfma_layer_kernel<256, 512, 0, 0><<<4096/64, 256, 0, stream>>>(
        h3aH, h3aL, w3bh, w3bl, b3b, h3bH, h3bL, nullptr, 0);
    mfma_layer_kernel<512, 1024, 0, 1><<<4096/64, 256, 0, stream>>>(
        h3bH, h3bL, w3ch, w3cl, b3c, nullptr, nullptr, h3c, 0);
    rowmax_kernel<<<ceil_div(32*1024, 256), 256, 0, stream>>>(h3c, f3, 32, 128, 1024);

    // ---- FC head (fp32)
    {
        dim3 g(ceil_div(512, 64), 1);
        gemm_kernel<1,0><<<g, 256, 0, stream>>>(f3, lin1, nullptr, fc1, 32, 512, 1024);
    }
    {
        dim3 g(ceil_div(256, 64), 1);
        gemm_kernel<1,0><<<g, 256, 0, stream>>>(fc1, lin2, nullptr, fc2, 32, 256, 512);
    }
    {
        dim3 g(1, 1);
        gemm_kernel<0,1><<<g, 256, 0, stream>>>(fc2, clsw, clsb, (float*)d_out, 32, 40, 256);
    }
}

// Round 13
// 2061.872 us; speedup vs baseline: 1.1940x; 1.1940x over previous
//
#include <hip/hip_runtime.h>

#define DEVFN __device__ __forceinline__

static inline int ceil_div(int a, int b) { return (a + b - 1) / b; }

typedef __attribute__((ext_vector_type(8))) short         bf16x8;  // 8 bf16 = 4 VGPR
typedef __attribute__((ext_vector_type(4))) float         f32x4;
typedef __attribute__((ext_vector_type(8))) unsigned short u16x8;

DEVFN unsigned short f2bf(float x) {           // RNE float->bf16 (finite inputs)
    unsigned u = __float_as_uint(x);
    unsigned r = ((u >> 16) & 1u) + 0x7fffu;
    return (unsigned short)((u + r) >> 16);
}
DEVFN float bf2f(unsigned short h) { return __uint_as_float(((unsigned)h) << 16); }

// ---------------------------------------------------------------------------
// DPP-based 64-lane max reduction step for a packed double key.
// ---------------------------------------------------------------------------
template<int CTRL>
DEVFN double dpp_max_step(double v)
{
    int lo = __double2loint(v), hi = __double2hiint(v);
    int tlo = __builtin_amdgcn_update_dpp(lo, lo, CTRL, 0xF, 0xF, false);
    int thi = __builtin_amdgcn_update_dpp(hi, hi, CTRL, 0xF, 0xF, false);
    return fmax(v, __hiloint2double(thi, tlo));
}

// ---------------------------------------------------------------------------
// Farthest point sampling — SINGLE WAVE per batch, packed-key argmax with
// 6-step DPP max reduce (unchanged; 202 µs @ N=1024).
// ---------------------------------------------------------------------------
template<int N>
__global__ __launch_bounds__(64) void fps_kernel(const float* __restrict__ xyz, int M,
                                                 int* __restrict__ out_idx,
                                                 float* __restrict__ nxout)
{
    constexpr int PPL = N / 64;
    int b = blockIdx.x, lane = threadIdx.x;
    __shared__ float4 sp[N];
    const float* p = xyz + (size_t)b * N * 3;
    float px[PPL], py[PPL], pz[PPL], dd[PPL];
    unsigned lo[PPL];
    #pragma unroll
    for (int j = 0; j < PPL; ++j) {
        int idx = lane + 64 * j;
        px[j] = p[idx*3+0]; py[j] = p[idx*3+1]; pz[j] = p[idx*3+2];
        sp[idx] = make_float4(px[j], py[j], pz[j], 0.f);
        dd[j] = 1e10f;
        lo[j] = ~(unsigned)idx;
    }
    __syncthreads();
    int far = 0;
    for (int s = 0; s < M; ++s) {
        float4 c4 = sp[far];
        if (lane == 0) {
            out_idx[(size_t)b*M + s] = far;
            nxout[((size_t)b*M + s)*3 + 0] = c4.x;
            nxout[((size_t)b*M + s)*3 + 1] = c4.y;
            nxout[((size_t)b*M + s)*3 + 2] = c4.z;
        }
        double cand[PPL];
        #pragma unroll
        for (int j = 0; j < PPL; ++j) {
            float dx = __fsub_rn(px[j], c4.x);
            float dy = __fsub_rn(py[j], c4.y);
            float dz = __fsub_rn(pz[j], c4.z);
            float d  = __fadd_rn(__fadd_rn(__fmul_rn(dx,dx), __fmul_rn(dy,dy)),
                                 __fmul_rn(dz,dz));
            float nd = fminf(dd[j], d);
            dd[j] = nd;
            cand[j] = __hiloint2double(__float_as_int(nd), (int)lo[j]);
        }
        #pragma unroll
        for (int st = PPL/2; st > 0; st >>= 1)
            #pragma unroll
            for (int j = 0; j < PPL; ++j)
                if (j < st) cand[j] = fmax(cand[j], cand[j + st]);
        double v = cand[0];
        v = dpp_max_step<0xB1>(v);
        v = dpp_max_step<0x4E>(v);
        v = dpp_max_step<0x124>(v);
        v = dpp_max_step<0x128>(v);
        v = dpp_max_step<0x142>(v);
        v = dpp_max_step<0x143>(v);
        int wlo = __builtin_amdgcn_readlane(__double2loint(v), 63);
        far = (int)(~(unsigned)wlo);
    }
}

// ---------------------------------------------------------------------------
// Ball query (unchanged).
// ---------------------------------------------------------------------------
__global__ void ballquery_kernel(const float* __restrict__ xyz,
                                 const float* __restrict__ new_xyz,
                                 int* __restrict__ gi,
                                 int B, int N, int M, int K, float r2)
{
    int t = blockIdx.x * blockDim.x + threadIdx.x;
    if (t >= B * M) return;
    int b = t / M;
    const float* p = xyz + (size_t)b * N * 3;
    float cx = new_xyz[t*3+0], cy = new_xyz[t*3+1], cz = new_xyz[t*3+2];
    int* out = gi + (size_t)t * K;
    int cnt = 0, first = 0;
    bool havefirst = false;
    for (int i = 0; i < N; ++i) {
        float dx = __fsub_rn(p[i*3+0], cx);
        float dy = __fsub_rn(p[i*3+1], cy);
        float dz = __fsub_rn(p[i*3+2], cz);
        float d  = __fadd_rn(__fadd_rn(__fmul_rn(dx,dx), __fmul_rn(dy,dy)),
                             __fmul_rn(dz,dz));
        if (d <= r2) {
            if (!havefirst) { first = i; havefirst = true; }
            out[cnt++] = i;
            if (cnt == K) break;
        }
    }
    for (; cnt < K; ++cnt) out[cnt] = first;
}

DEVFN float f4_elem(const float4& v, int u) {
    return u == 0 ? v.x : u == 1 ? v.y : u == 2 ? v.z : v.w;
}

// ---------------------------------------------------------------------------
// Weight split+transpose prep: w [CI][CO] fp32 -> wh/wl [CO][CI] bf16 pair.
// ---------------------------------------------------------------------------
__global__ void wsplit_kernel(const float* __restrict__ w,
                              unsigned short* __restrict__ wh,
                              unsigned short* __restrict__ wl, int CI, int CO)
{
    int t = blockIdx.x * 256 + threadIdx.x;
    if (t >= CI * CO) return;
    int co = t / CI, ci = t % CI;
    float v = w[(size_t)ci * CO + co];
    unsigned short h = f2bf(v);
    wh[t] = h;
    wl[t] = f2bf(v - bf2f(h));
}

// Elementwise fp32 -> split bf16 pair (same layout).
__global__ void asplit_kernel(const float* __restrict__ a,
                              unsigned short* __restrict__ ah,
                              unsigned short* __restrict__ al, int n)
{
    int t = blockIdx.x * 256 + threadIdx.x;
    if (t >= n) return;
    float v = a[t];
    unsigned short h = f2bf(v);
    ah[t] = h;
    al[t] = f2bf(v - bf2f(h));
}

// ---------------------------------------------------------------------------
// SA layer 1 (fused gather + centering), fp32 VALU, writing ROW-MAJOR
// split-bf16 activations for the MFMA layers (unchanged from R12).
// ---------------------------------------------------------------------------
template<int CF, int CO, int KPTS>
__global__ __launch_bounds__(256) void sa_l1_kernel(
    const float* __restrict__ xyz, const float* __restrict__ feats,
    const float* __restrict__ new_xyz, const int* __restrict__ gi,
    const float* __restrict__ w, const float* __restrict__ bias,
    unsigned short* __restrict__ oh, unsigned short* __restrict__ ol,
    int N, int M, int row0)
{
    constexpr int WCH = CO / 4;
    const int lane = threadIdx.x & 63;
    const int wv   = __builtin_amdgcn_readfirstlane(threadIdx.x >> 6);
    const int rl   = blockIdx.x * 64 + lane;
    const int row  = row0 + rl;
    const int cent = row / KPTS;
    const int b    = cent / M;
    const int idx  = gi[row];
    const float* pp  = xyz + ((size_t)b*N + idx)*3;
    const float* cc3 = new_xyz + (size_t)cent*3;
    float a0 = __fsub_rn(pp[0], cc3[0]);
    float a1 = __fsub_rn(pp[1], cc3[1]);
    float a2 = __fsub_rn(pp[2], cc3[2]);
    const float* frow = feats + ((size_t)b*N + idx)*CF;
    const float* wcol = w + wv*WCH;
    const float* bcol = bias + wv*WCH;
    float acc[WCH];
    #pragma unroll
    for (int j = 0; j < WCH; ++j) acc[j] = bcol[j];
    #pragma unroll
    for (int j = 0; j < WCH; ++j) acc[j] += a0 * wcol[0*CO + j];
    #pragma unroll
    for (int j = 0; j < WCH; ++j) acc[j] += a1 * wcol[1*CO + j];
    #pragma unroll
    for (int j = 0; j < WCH; ++j) acc[j] += a2 * wcol[2*CO + j];
    constexpr int CF4 = CF & ~3;
    #pragma unroll 2
    for (int cc = 0; cc < CF4; cc += 4) {
        float4 a4 = *(const float4*)(frow + cc);
        #pragma unroll
        for (int u = 0; u < 4; ++u) {
            float a = f4_elem(a4, u);
            #pragma unroll
            for (int j = 0; j < WCH; ++j)
                acc[j] += a * wcol[(size_t)(3 + cc + u)*CO + j];
        }
    }
    #pragma unroll
    for (int f = CF4; f < CF; ++f) {
        float a = frow[f];
        #pragma unroll
        for (int j = 0; j < WCH; ++j)
            acc[j] += a * wcol[(size_t)(3 + f)*CO + j];
    }
    #pragma unroll
    for (int j8 = 0; j8 < WCH; j8 += 8) {
        u16x8 hv, lv;
        #pragma unroll
        for (int u = 0; u < 8; ++u) {
            float v = fmaxf(acc[j8+u], 0.f);
            unsigned short h = f2bf(v);
            hv[u] = (unsigned short)h;
            lv[u] = f2bf(v - bf2f(h));
        }
        size_t o = (size_t)rl*CO + wv*WCH + j8;
        *(u16x8*)(&oh[o]) = hv;
        *(u16x8*)(&ol[o]) = lv;
    }
}

// ---------------------------------------------------------------------------
// MFMA layer with COLUMN TILING: act row-major split bf16 [R][CI] x weights
// [CO][CI] split bf16 -> bias+relu. Two-split: Ah*Bh + Ah*Bl + Al*Bh.
// grid = (rows/64, CO/(16*NTILE)); block = 256 thr = 4 waves, 64 rows.
// Wave owns 16 rows x (16*NTILE) cols starting at colbase.
// Fragment layout (v_mfma_f32_16x16x32_bf16):
//   A: a[j] = A[lane&15][(lane>>4)*8 + j]   B: b[j] = B[(lane>>4)*8+j][lane&15]
//   D: d[r] = D[(lane>>4)*4 + r][lane&15]
// OUTMODE: 0 = split-bf16 out, 1 = fp32 row-major out, 2 = maxpool(KPTS)->fp32
// ---------------------------------------------------------------------------
template<int CI, int CO, int NTILE, int KPTS, int OUTMODE>
__global__ __launch_bounds__(256) void mfma_layer_kernel(
    const unsigned short* __restrict__ ah, const unsigned short* __restrict__ al,
    const unsigned short* __restrict__ wh, const unsigned short* __restrict__ wl,
    const float* __restrict__ bias,
    unsigned short* __restrict__ oh, unsigned short* __restrict__ ol,
    float* __restrict__ ofp, int rowbase)
{
    constexpr int KT = CI / 32;
    constexpr bool PRE = (KT <= 8);
    __shared__ float partial[4][OUTMODE == 2 ? 16*NTILE : 1];
    const int wid  = threadIdx.x >> 6;
    const int lane = threadIdx.x & 63;
    const int m    = lane & 15;
    const int kg   = lane >> 4;
    const int row0 = blockIdx.x * 64 + wid * 16;
    const int colbase = blockIdx.y * (16 * NTILE);
    const unsigned short* arh = ah + (size_t)(row0 + m) * CI + kg * 8;
    const unsigned short* arl = al + (size_t)(row0 + m) * CI + kg * 8;
    bf16x8 Ahf[PRE ? KT : 1], Alf[PRE ? KT : 1];
    if constexpr (PRE) {
        #pragma unroll
        for (int kt = 0; kt < KT; ++kt) {
            Ahf[kt] = *(const bf16x8*)(arh + kt*32);
            Alf[kt] = *(const bf16x8*)(arl + kt*32);
        }
    }
    #pragma unroll
    for (int nt = 0; nt < NTILE; ++nt) {
        f32x4 acc = {0.f, 0.f, 0.f, 0.f};
        const unsigned short* wbh = wh + (size_t)(colbase + nt*16 + m) * CI + kg * 8;
        const unsigned short* wbl = wl + (size_t)(colbase + nt*16 + m) * CI + kg * 8;
        #pragma unroll 4
        for (int kt = 0; kt < KT; ++kt) {
            bf16x8 Bh = *(const bf16x8*)(wbh + kt*32);
            bf16x8 Bl = *(const bf16x8*)(wbl + kt*32);
            bf16x8 a_h, a_l;
            if constexpr (PRE) { a_h = Ahf[kt]; a_l = Alf[kt]; }
            else {
                a_h = *(const bf16x8*)(arh + kt*32);
                a_l = *(const bf16x8*)(arl + kt*32);
            }
            acc = __builtin_amdgcn_mfma_f32_16x16x32_bf16(a_h, Bh, acc, 0, 0, 0);
            acc = __builtin_amdgcn_mfma_f32_16x16x32_bf16(a_h, Bl, acc, 0, 0, 0);
            acc = __builtin_amdgcn_mfma_f32_16x16x32_bf16(a_l, Bh, acc, 0, 0, 0);
        }
        int dcol = colbase + nt*16 + m;
        float bv = bias[dcol];
        float v[4];
        #pragma unroll
        for (int r = 0; r < 4; ++r) v[r] = fmaxf(acc[r] + bv, 0.f);
        if constexpr (OUTMODE == 0) {
            #pragma unroll
            for (int r = 0; r < 4; ++r) {
                size_t o = (size_t)(row0 + kg*4 + r) * CO + dcol;
                unsigned short h = f2bf(v[r]);
                oh[o] = h;
                ol[o] = f2bf(v[r] - bf2f(h));
            }
        } else if constexpr (OUTMODE == 1) {
            #pragma unroll
            for (int r = 0; r < 4; ++r)
                ofp[(size_t)(row0 + kg*4 + r) * CO + dcol] = v[r];
        } else {
            float mx = fmaxf(fmaxf(v[0], v[1]), fmaxf(v[2], v[3]));
            mx = fmaxf(mx, __shfl_xor(mx, 16));
            mx = fmaxf(mx, __shfl_xor(mx, 32));
            if (lane < 16) partial[wid][nt*16 + m] = mx;
        }
    }
    if constexpr (OUTMODE == 2) {
        __syncthreads();
        for (int c = threadIdx.x; c < 16*NTILE; c += 256) {
            if constexpr (KPTS == 64) {
                float mx = fmaxf(fmaxf(partial[0][c], partial[1][c]),
                                 fmaxf(partial[2][c], partial[3][c]));
                int cent = (rowbase + blockIdx.x*64) / 64;
                ofp[(size_t)cent*CO + colbase + c] = mx;
            } else {               // KPTS == 32: block covers 2 centroids
                int cent0 = (rowbase + blockIdx.x*64) / 32;
                ofp[(size_t)cent0*CO + colbase + c]     = fmaxf(partial[0][c], partial[1][c]);
                ofp[(size_t)(cent0+1)*CO + colbase + c] = fmaxf(partial[2][c], partial[3][c]);
            }
        }
    }
}

// ---------------------------------------------------------------------------
// concat [R,3] ++ [R,CF] -> [R,3+CF]
// ---------------------------------------------------------------------------
__global__ void concat_kernel(const float* __restrict__ a, const float* __restrict__ f,
                              float* __restrict__ out, int R, int CF)
{
    int C = CF + 3;
    int t = blockIdx.x * blockDim.x + threadIdx.x;
    if (t >= R * C) return;
    int r = t / C, c = t % C;
    out[t] = (c < 3) ? a[r*3 + c] : f[(size_t)r * CF + (c - 3)];
}

// ---------------------------------------------------------------------------
// Tiled fp32 GEMM, 64x64 tile / 4x4 micro (K=259 layer + FC head).
// ---------------------------------------------------------------------------
template<int RELU, int HASB>
__global__ __launch_bounds__(256) void gemm_kernel(
    const float* __restrict__ A, const float* __restrict__ W,
    const float* __restrict__ bias, float* __restrict__ Cc,
    int Mr, int Nc, int Kd)
{
    __shared__ float As[64][17];
    __shared__ float Ws[16][65];
    int tx = threadIdx.x % 16;
    int ty = threadIdx.x / 16;
    int row0 = blockIdx.y * 64;
    int col0 = blockIdx.x * 64;
    float acc[4][4] = {};
    for (int k0 = 0; k0 < Kd; k0 += 16) {
        for (int t = threadIdx.x; t < 64*16; t += 256) {
            int r = t >> 4, kk = t & 15;
            int gr = row0 + r, gk = k0 + kk;
            As[r][kk] = (gr < Mr && gk < Kd) ? A[(size_t)gr * Kd + gk] : 0.f;
        }
        for (int t = threadIdx.x; t < 16*64; t += 256) {
            int kk = t >> 6, c = t & 63;
            int gk = k0 + kk, gc = col0 + c;
            Ws[kk][c] = (gk < Kd && gc < Nc) ? W[(size_t)gk * Nc + gc] : 0.f;
        }
        __syncthreads();
        #pragma unroll
        for (int kk = 0; kk < 16; ++kk) {
            float av[4], wv[4];
            #pragma unroll
            for (int i = 0; i < 4; i++) av[i] = As[ty*4+i][kk];
            #pragma unroll
            for (int j = 0; j < 4; j++) wv[j] = Ws[kk][tx*4+j];
            #pragma unroll
            for (int i = 0; i < 4; i++)
                #pragma unroll
                for (int j = 0; j < 4; j++)
                    acc[i][j] += av[i] * wv[j];
        }
        __syncthreads();
    }
    #pragma unroll
    for (int i = 0; i < 4; i++) {
        int gr = row0 + ty*4 + i;
        if (gr >= Mr) continue;
        #pragma unroll
        for (int j = 0; j < 4; j++) {
            int gc = col0 + tx*4 + j;
            if (gc >= Nc) continue;
            float v = acc[i][j];
            if (HASB) v += bias[gc];
            if (RELU) v = fmaxf(v, 0.f);
            Cc[(size_t)gr * Nc + gc] = v;
        }
    }
}

// ---------------------------------------------------------------------------
// Max over P points: in [B,P,C] -> out [B,C]
// ---------------------------------------------------------------------------
__global__ void rowmax_kernel(const float* __restrict__ in, float* __restrict__ out,
                              int B, int P, int C)
{
    int t = blockIdx.x * blockDim.x + threadIdx.x;
    if (t >= B * C) return;
    int b = t / C, c = t % C;
    const float* p = in + (size_t)b * P * C + c;
    float mx = p[0];
    for (int i = 1; i < P; ++i) mx = fmaxf(mx, p[(size_t)i * C]);
    out[t] = mx;
}

// ---------------------------------------------------------------------------
extern "C" void kernel_launch(void* const* d_in, const int* in_sizes, int n_in,
                              void* d_out, int out_size, void* d_ws, size_t ws_size,
                              hipStream_t stream)
{
    const float* xyz    = (const float*)d_in[0];
    const float* points = (const float*)d_in[1];
    const float* w1a = (const float*)d_in[2];  const float* b1a = (const float*)d_in[3];
    const float* w1b = (const float*)d_in[4];  const float* b1b = (const float*)d_in[5];
    const float* w1c = (const float*)d_in[6];  const float* b1c = (const float*)d_in[7];
    const float* w2a = (const float*)d_in[8];  const float* b2a = (const float*)d_in[9];
    const float* w2b = (const float*)d_in[10]; const float* b2b = (const float*)d_in[11];
    const float* w2c = (const float*)d_in[12]; const float* b2c = (const float*)d_in[13];
    const float* w3a = (const float*)d_in[14]; const float* b3a = (const float*)d_in[15];
    const float* w3b = (const float*)d_in[16]; const float* b3b = (const float*)d_in[17];
    const float* w3c = (const float*)d_in[18]; const float* b3c = (const float*)d_in[19];
    const float* lin1 = (const float*)d_in[20];
    const float* lin2 = (const float*)d_in[21];
    const float* clsw = (const float*)d_in[22];
    const float* clsb = (const float*)d_in[23];

    char* ws = (char*)d_ws;
    size_t off = 0;
    auto alloc = [&](size_t bytes) -> void* {
        void* p = ws + off;
        off += (bytes + 255) & ~(size_t)255;
        return p;
    };
    int*   fps1 = (int*)  alloc((size_t)32*512*4);
    float* nx1  = (float*)alloc((size_t)32*512*3*4);
    int*   gi1  = (int*)  alloc((size_t)32*512*32*4);
    float* f1   = (float*)alloc((size_t)32*512*128*4);
    int*   fps2 = (int*)  alloc((size_t)32*128*4);
    float* nx2  = (float*)alloc((size_t)32*128*3*4);
    int*   gi2  = (int*)  alloc((size_t)32*128*64*4);
    float* f2   = (float*)alloc((size_t)32*128*256*4);
    float* g3   = (float*)alloc((size_t)4096*259*4);
    float* h3a  = (float*)alloc((size_t)4096*256*4);
    float* h3c  = (float*)alloc((size_t)4096*1024*4);
    float* f3   = (float*)alloc((size_t)32*1024*4);
    float* fc1  = (float*)alloc((size_t)32*512*4);
    float* fc2  = (float*)alloc((size_t)32*256*4);

    typedef unsigned short us;
    // split weights (transposed [CO][CI], bf16 hi/lo)
    us* w1bh = (us*)alloc(64*64*2);     us* w1bl = (us*)alloc(64*64*2);
    us* w1ch = (us*)alloc(128*64*2);    us* w1cl = (us*)alloc(128*64*2);
    us* w2bh = (us*)alloc(128*128*2);   us* w2bl = (us*)alloc(128*128*2);
    us* w2ch = (us*)alloc(256*128*2);   us* w2cl = (us*)alloc(256*128*2);
    us* w3bh = (us*)alloc(512*256*2);   us* w3bl = (us*)alloc(512*256*2);
    us* w3ch = (us*)alloc(1024*512*2);  us* w3cl = (us*)alloc(1024*512*2);
    // split SA3 activations
    us* h3aH = (us*)alloc((size_t)4096*256*2);  us* h3aL = (us*)alloc((size_t)4096*256*2);
    us* h3bH = (us*)alloc((size_t)4096*512*2);  us* h3bL = (us*)alloc((size_t)4096*512*2);

    // big split activation ping-pong buffers (hi/lo per side)
    size_t avail = (ws_size > off + 1024) ? (ws_size - off - 1024) : 0;
    size_t bufcap = avail / 4;
    if (bufcap > (size_t)67200000) bufcap = 67200000;   // 524288 rows x 64ch x 2B
    us* Ah = (us*)alloc(bufcap); us* Al = (us*)alloc(bufcap);
    us* Bh = (us*)alloc(bufcap); us* Bl = (us*)alloc(bufcap);

    // ---- weight prep (independent of data flow)
    auto wsp = [&](const float* w, int CI, int CO, us* wh, us* wl) {
        wsplit_kernel<<<ceil_div(CI*CO, 256), 256, 0, stream>>>(w, wh, wl, CI, CO);
    };
    wsp(w1b, 64, 64,  w1bh, w1bl);
    wsp(w1c, 64, 128, w1ch, w1cl);
    wsp(w2b, 128, 128, w2bh, w2bl);
    wsp(w2c, 128, 256, w2ch, w2cl);
    wsp(w3b, 256, 512, w3bh, w3bl);
    wsp(w3c, 512, 1024, w3ch, w3cl);

    // ---- SA1: N=1024 -> M=512, r=0.2, K=32, MLP 6->64->64->128
    fps_kernel<1024><<<32, 64, 0, stream>>>(xyz, 512, fps1, nx1);
    ballquery_kernel<<<ceil_div(32*512, 256), 256, 0, stream>>>(
        xyz, nx1, gi1, 32, 1024, 512, 32, (float)(0.2*0.2));
    {
        const int rows = 32*512*32;                     // 524288
        int ch = (int)((bufcap / (64*2)) & ~(size_t)255);
        if (ch > rows) ch = rows;
        if (ch < 256) ch = 256;
        for (int r0 = 0; r0 < rows; r0 += ch) {
            int rc = rows - r0 < ch ? rows - r0 : ch;
            sa_l1_kernel<3, 64, 32><<<rc/64, 256, 0, stream>>>(
                xyz, points, nx1, gi1, w1a, b1a, Ah, Al, 1024, 512, r0);
            mfma_layer_kernel<64, 64, 4, 0, 0><<<dim3(rc/64, 1), 256, 0, stream>>>(
                Ah, Al, w1bh, w1bl, b1b, Bh, Bl, nullptr, 0);
            mfma_layer_kernel<64, 128, 8, 32, 2><<<dim3(rc/64, 1), 256, 0, stream>>>(
                Bh, Bl, w1ch, w1cl, b1c, nullptr, nullptr, f1, r0);
        }
    }

    // ---- SA2: N=512 -> M=128, r=0.4, K=64, MLP 131->128->128->256
    fps_kernel<512><<<32, 64, 0, stream>>>(nx1, 128, fps2, nx2);
    ballquery_kernel<<<ceil_div(32*128, 256), 256, 0, stream>>>(
        nx1, nx2, gi2, 32, 512, 128, 64, (float)(0.4*0.4));
    {
        const int rows = 32*128*64;                     // 262144
        int ch = (int)((bufcap / (128*2)) & ~(size_t)255);
        if (ch > rows) ch = rows;
        if (ch < 256) ch = 256;
        for (int r0 = 0; r0 < rows; r0 += ch) {
            int rc = rows - r0 < ch ? rows - r0 : ch;
            sa_l1_kernel<128, 128, 64><<<rc/64, 256, 0, stream>>>(
                nx1, f1, nx2, gi2, w2a, b2a, Ah, Al, 512, 128, r0);
            mfma_layer_kernel<128, 128, 8, 0, 0><<<dim3(rc/64, 1), 256, 0, stream>>>(
                Ah, Al, w2bh, w2bl, b2b, Bh, Bl, nullptr, 0);
            mfma_layer_kernel<128, 256, 16, 64, 2><<<dim3(rc/64, 1), 256, 0, stream>>>(
                Bh, Bl, w2ch, w2cl, b2c, nullptr, nullptr, f2, r0);
        }
    }

    // ---- SA3 (group_all): concat [4096,259] -> 259->256 (fp32 gemm) ->
    //      256->512 (mfma, col-tiled) -> 512->1024 (mfma, col-tiled) -> max over 128
    concat_kernel<<<ceil_div(4096*259, 256), 256, 0, stream>>>(nx2, f2, g3, 4096, 256);
    {
        dim3 g(ceil_div(256, 64), ceil_div(4096, 64));
        gemm_kernel<1,1><<<g, 256, 0, stream>>>(g3, w3a, b3a, h3a, 4096, 256, 259);
    }
    asplit_kernel<<<ceil_div(4096*256, 256), 256, 0, stream>>>(h3a, h3aH, h3aL, 4096*256);
    // 256->512: NTILE=2 -> grid (64, 16) = 1024 blocks; KT=8 preloads A.
    mfma_layer_kernel<256, 512, 2, 0, 0><<<dim3(4096/64, 512/32), 256, 0, stream>>>(
        h3aH, h3aL, w3bh, w3bl, b3b, h3bH, h3bL, nullptr, 0);
    // 512->1024: NTILE=4 -> grid (64, 16) = 1024 blocks.
    mfma_layer_kernel<512, 1024, 4, 0, 1><<<dim3(4096/64, 1024/64), 256, 0, stream>>>(
        h3bH, h3bL, w3ch, w3cl, b3c, nullptr, nullptr, h3c, 0);
    rowmax_kernel<<<ceil_div(32*1024, 256), 256, 0, stream>>>(h3c, f3, 32, 128, 1024);

    // ---- FC head (fp32)
    {
        dim3 g(ceil_div(512, 64), 1);
        gemm_kernel<1,0><<<g, 256, 0, stream>>>(f3, lin1, nullptr, fc1, 32, 512, 1024);
    }
    {
        dim3 g(ceil_div(256, 64), 1);
        gemm_kernel<1,0><<<g, 256, 0, stream>>>(fc1, lin2, nullptr, fc2, 32, 256, 512);
    }
    {
        dim3 g(1, 1);
        gemm_kernel<0,1><<<g, 256, 0, stream>>>(fc2, clsw, clsb, (float*)d_out, 32, 40, 256);
    }
}

// Round 14
// 1589.111 us; speedup vs baseline: 1.5492x; 1.2975x over previous
//
#include <hip/hip_runtime.h>

#define DEVFN __device__ __forceinline__

static inline int ceil_div(int a, int b) { return (a + b - 1) / b; }

typedef __attribute__((ext_vector_type(8))) short         bf16x8;  // 8 bf16 = 4 VGPR
typedef __attribute__((ext_vector_type(4))) float         f32x4;
typedef __attribute__((ext_vector_type(8))) unsigned short u16x8;

DEVFN unsigned short f2bf(float x) {           // RNE float->bf16 (finite inputs)
    unsigned u = __float_as_uint(x);
    unsigned r = ((u >> 16) & 1u) + 0x7fffu;
    return (unsigned short)((u + r) >> 16);
}
DEVFN float bf2f(unsigned short h) { return __uint_as_float(((unsigned)h) << 16); }

// ---------------------------------------------------------------------------
// DPP-based 64-lane max reduction step for a packed double key.
// ---------------------------------------------------------------------------
template<int CTRL>
DEVFN double dpp_max_step(double v)
{
    int lo = __double2loint(v), hi = __double2hiint(v);
    int tlo = __builtin_amdgcn_update_dpp(lo, lo, CTRL, 0xF, 0xF, false);
    int thi = __builtin_amdgcn_update_dpp(hi, hi, CTRL, 0xF, 0xF, false);
    return fmax(v, __hiloint2double(thi, tlo));
}

// ---------------------------------------------------------------------------
// Farthest point sampling — SINGLE WAVE per batch, packed-key argmax with
// 6-step DPP max reduce (unchanged; 202 µs @ N=1024).
// ---------------------------------------------------------------------------
template<int N>
__global__ __launch_bounds__(64) void fps_kernel(const float* __restrict__ xyz, int M,
                                                 int* __restrict__ out_idx,
                                                 float* __restrict__ nxout)
{
    constexpr int PPL = N / 64;
    int b = blockIdx.x, lane = threadIdx.x;
    __shared__ float4 sp[N];
    const float* p = xyz + (size_t)b * N * 3;
    float px[PPL], py[PPL], pz[PPL], dd[PPL];
    unsigned lo[PPL];
    #pragma unroll
    for (int j = 0; j < PPL; ++j) {
        int idx = lane + 64 * j;
        px[j] = p[idx*3+0]; py[j] = p[idx*3+1]; pz[j] = p[idx*3+2];
        sp[idx] = make_float4(px[j], py[j], pz[j], 0.f);
        dd[j] = 1e10f;
        lo[j] = ~(unsigned)idx;
    }
    __syncthreads();
    int far = 0;
    for (int s = 0; s < M; ++s) {
        float4 c4 = sp[far];
        if (lane == 0) {
            out_idx[(size_t)b*M + s] = far;
            nxout[((size_t)b*M + s)*3 + 0] = c4.x;
            nxout[((size_t)b*M + s)*3 + 1] = c4.y;
            nxout[((size_t)b*M + s)*3 + 2] = c4.z;
        }
        double cand[PPL];
        #pragma unroll
        for (int j = 0; j < PPL; ++j) {
            float dx = __fsub_rn(px[j], c4.x);
            float dy = __fsub_rn(py[j], c4.y);
            float dz = __fsub_rn(pz[j], c4.z);
            float d  = __fadd_rn(__fadd_rn(__fmul_rn(dx,dx), __fmul_rn(dy,dy)),
                                 __fmul_rn(dz,dz));
            float nd = fminf(dd[j], d);
            dd[j] = nd;
            cand[j] = __hiloint2double(__float_as_int(nd), (int)lo[j]);
        }
        #pragma unroll
        for (int st = PPL/2; st > 0; st >>= 1)
            #pragma unroll
            for (int j = 0; j < PPL; ++j)
                if (j < st) cand[j] = fmax(cand[j], cand[j + st]);
        double v = cand[0];
        v = dpp_max_step<0xB1>(v);
        v = dpp_max_step<0x4E>(v);
        v = dpp_max_step<0x124>(v);
        v = dpp_max_step<0x128>(v);
        v = dpp_max_step<0x142>(v);
        v = dpp_max_step<0x143>(v);
        int wlo = __builtin_amdgcn_readlane(__double2loint(v), 63);
        far = (int)(~(unsigned)wlo);
    }
}

// ---------------------------------------------------------------------------
// Ball query (unchanged).
// ---------------------------------------------------------------------------
__global__ void ballquery_kernel(const float* __restrict__ xyz,
                                 const float* __restrict__ new_xyz,
                                 int* __restrict__ gi,
                                 int B, int N, int M, int K, float r2)
{
    int t = blockIdx.x * blockDim.x + threadIdx.x;
    if (t >= B * M) return;
    int b = t / M;
    const float* p = xyz + (size_t)b * N * 3;
    float cx = new_xyz[t*3+0], cy = new_xyz[t*3+1], cz = new_xyz[t*3+2];
    int* out = gi + (size_t)t * K;
    int cnt = 0, first = 0;
    bool havefirst = false;
    for (int i = 0; i < N; ++i) {
        float dx = __fsub_rn(p[i*3+0], cx);
        float dy = __fsub_rn(p[i*3+1], cy);
        float dz = __fsub_rn(p[i*3+2], cz);
        float d  = __fadd_rn(__fadd_rn(__fmul_rn(dx,dx), __fmul_rn(dy,dy)),
                             __fmul_rn(dz,dz));
        if (d <= r2) {
            if (!havefirst) { first = i; havefirst = true; }
            out[cnt++] = i;
            if (cnt == K) break;
        }
    }
    for (; cnt < K; ++cnt) out[cnt] = first;
}

DEVFN float f4_elem(const float4& v, int u) {
    return u == 0 ? v.x : u == 1 ? v.y : u == 2 ? v.z : v.w;
}

// ---------------------------------------------------------------------------
// Weight split+transpose prep: w [CI][CO] fp32 -> wh/wl [CO][CI] bf16 pair.
// ---------------------------------------------------------------------------
__global__ void wsplit_kernel(const float* __restrict__ w,
                              unsigned short* __restrict__ wh,
                              unsigned short* __restrict__ wl, int CI, int CO)
{
    int t = blockIdx.x * 256 + threadIdx.x;
    if (t >= CI * CO) return;
    int co = t / CI, ci = t % CI;
    float v = w[(size_t)ci * CO + co];
    unsigned short h = f2bf(v);
    wh[t] = h;
    wl[t] = f2bf(v - bf2f(h));
}

// Elementwise fp32 -> split bf16 pair (same layout).
__global__ void asplit_kernel(const float* __restrict__ a,
                              unsigned short* __restrict__ ah,
                              unsigned short* __restrict__ al, int n)
{
    int t = blockIdx.x * 256 + threadIdx.x;
    if (t >= n) return;
    float v = a[t];
    unsigned short h = f2bf(v);
    ah[t] = h;
    al[t] = f2bf(v - bf2f(h));
}

// ---------------------------------------------------------------------------
// SA layer 1 (fused gather + centering), fp32 VALU, writing ROW-MAJOR
// split-bf16 activations for the MFMA layers (unchanged from R12).
// ---------------------------------------------------------------------------
template<int CF, int CO, int KPTS>
__global__ __launch_bounds__(256) void sa_l1_kernel(
    const float* __restrict__ xyz, const float* __restrict__ feats,
    const float* __restrict__ new_xyz, const int* __restrict__ gi,
    const float* __restrict__ w, const float* __restrict__ bias,
    unsigned short* __restrict__ oh, unsigned short* __restrict__ ol,
    int N, int M, int row0)
{
    constexpr int WCH = CO / 4;
    const int lane = threadIdx.x & 63;
    const int wv   = __builtin_amdgcn_readfirstlane(threadIdx.x >> 6);
    const int rl   = blockIdx.x * 64 + lane;
    const int row  = row0 + rl;
    const int cent = row / KPTS;
    const int b    = cent / M;
    const int idx  = gi[row];
    const float* pp  = xyz + ((size_t)b*N + idx)*3;
    const float* cc3 = new_xyz + (size_t)cent*3;
    float a0 = __fsub_rn(pp[0], cc3[0]);
    float a1 = __fsub_rn(pp[1], cc3[1]);
    float a2 = __fsub_rn(pp[2], cc3[2]);
    const float* frow = feats + ((size_t)b*N + idx)*CF;
    const float* wcol = w + wv*WCH;
    const float* bcol = bias + wv*WCH;
    float acc[WCH];
    #pragma unroll
    for (int j = 0; j < WCH; ++j) acc[j] = bcol[j];
    #pragma unroll
    for (int j = 0; j < WCH; ++j) acc[j] += a0 * wcol[0*CO + j];
    #pragma unroll
    for (int j = 0; j < WCH; ++j) acc[j] += a1 * wcol[1*CO + j];
    #pragma unroll
    for (int j = 0; j < WCH; ++j) acc[j] += a2 * wcol[2*CO + j];
    constexpr int CF4 = CF & ~3;
    #pragma unroll 2
    for (int cc = 0; cc < CF4; cc += 4) {
        float4 a4 = *(const float4*)(frow + cc);
        #pragma unroll
        for (int u = 0; u < 4; ++u) {
            float a = f4_elem(a4, u);
            #pragma unroll
            for (int j = 0; j < WCH; ++j)
                acc[j] += a * wcol[(size_t)(3 + cc + u)*CO + j];
        }
    }
    #pragma unroll
    for (int f = CF4; f < CF; ++f) {
        float a = frow[f];
        #pragma unroll
        for (int j = 0; j < WCH; ++j)
            acc[j] += a * wcol[(size_t)(3 + f)*CO + j];
    }
    #pragma unroll
    for (int j8 = 0; j8 < WCH; j8 += 8) {
        u16x8 hv, lv;
        #pragma unroll
        for (int u = 0; u < 8; ++u) {
            float v = fmaxf(acc[j8+u], 0.f);
            unsigned short h = f2bf(v);
            hv[u] = (unsigned short)h;
            lv[u] = f2bf(v - bf2f(h));
        }
        size_t o = (size_t)rl*CO + wv*WCH + j8;
        *(u16x8*)(&oh[o]) = hv;
        *(u16x8*)(&ol[o]) = lv;
    }
}

// ---------------------------------------------------------------------------
// MFMA layer with column tiling + MROW row-tiles per wave: each wave owns
// MROW 16-row tiles; B-fragments loaded once per (nt,kt) feed 3*MROW MFMAs
// into MROW independent acc chains (amortizes weight loads, breaks the
// dependency stall). A preloaded in registers (MROW*KT <= 16 -> <=128 VGPR).
// grid = (rows/(64*MROW), CO/(16*NTILE)); block = 256 thr = 4 waves.
// Fragment layout (v_mfma_f32_16x16x32_bf16):
//   A: a[j] = A[lane&15][(lane>>4)*8 + j]   B: b[j] = B[(lane>>4)*8+j][lane&15]
//   D: d[r] = D[(lane>>4)*4 + r][lane&15]
// OUTMODE: 0 = split-bf16 out, 1 = fp32 row-major out, 2 = maxpool(KPTS)->fp32
// ---------------------------------------------------------------------------
template<int CI, int CO, int NTILE, int MROW, int KPTS, int OUTMODE>
__global__ __launch_bounds__(256) void mfma_layer_kernel(
    const unsigned short* __restrict__ ah, const unsigned short* __restrict__ al,
    const unsigned short* __restrict__ wh, const unsigned short* __restrict__ wl,
    const float* __restrict__ bias,
    unsigned short* __restrict__ oh, unsigned short* __restrict__ ol,
    float* __restrict__ ofp, int rowbase)
{
    constexpr int KT = CI / 32;
    static_assert(KT * MROW <= 16, "A-preload register budget");
    __shared__ float partial[4][OUTMODE == 2 ? MROW : 1][OUTMODE == 2 ? 16*NTILE : 1];
    const int wid  = threadIdx.x >> 6;
    const int lane = threadIdx.x & 63;
    const int m    = lane & 15;
    const int kg   = lane >> 4;
    const int blockrow = blockIdx.x * (64 * MROW);
    const int colbase  = blockIdx.y * (16 * NTILE);
    bf16x8 Ahf[MROW * KT], Alf[MROW * KT];
    #pragma unroll
    for (int t = 0; t < MROW; ++t) {
        const unsigned short* arh =
            ah + (size_t)(blockrow + t*64 + wid*16 + m) * CI + kg * 8;
        const unsigned short* arl =
            al + (size_t)(blockrow + t*64 + wid*16 + m) * CI + kg * 8;
        #pragma unroll
        for (int kt = 0; kt < KT; ++kt) {
            Ahf[t*KT + kt] = *(const bf16x8*)(arh + kt*32);
            Alf[t*KT + kt] = *(const bf16x8*)(arl + kt*32);
        }
    }
    #pragma unroll
    for (int nt = 0; nt < NTILE; ++nt) {
        f32x4 acc[MROW];
        #pragma unroll
        for (int t = 0; t < MROW; ++t) acc[t] = (f32x4){0.f, 0.f, 0.f, 0.f};
        const unsigned short* wbh = wh + (size_t)(colbase + nt*16 + m) * CI + kg * 8;
        const unsigned short* wbl = wl + (size_t)(colbase + nt*16 + m) * CI + kg * 8;
        #pragma unroll
        for (int kt = 0; kt < KT; ++kt) {
            bf16x8 Bh = *(const bf16x8*)(wbh + kt*32);
            bf16x8 Bl = *(const bf16x8*)(wbl + kt*32);
            #pragma unroll
            for (int t = 0; t < MROW; ++t) {
                acc[t] = __builtin_amdgcn_mfma_f32_16x16x32_bf16(Ahf[t*KT+kt], Bh, acc[t], 0, 0, 0);
                acc[t] = __builtin_amdgcn_mfma_f32_16x16x32_bf16(Ahf[t*KT+kt], Bl, acc[t], 0, 0, 0);
                acc[t] = __builtin_amdgcn_mfma_f32_16x16x32_bf16(Alf[t*KT+kt], Bh, acc[t], 0, 0, 0);
            }
        }
        int dcol = colbase + nt*16 + m;
        float bv = bias[dcol];
        #pragma unroll
        for (int t = 0; t < MROW; ++t) {
            float v[4];
            #pragma unroll
            for (int r = 0; r < 4; ++r) v[r] = fmaxf(acc[t][r] + bv, 0.f);
            if constexpr (OUTMODE == 0) {
                #pragma unroll
                for (int r = 0; r < 4; ++r) {
                    size_t o = (size_t)(blockrow + t*64 + wid*16 + kg*4 + r) * CO + dcol;
                    unsigned short h = f2bf(v[r]);
                    oh[o] = h;
                    ol[o] = f2bf(v[r] - bf2f(h));
                }
            } else if constexpr (OUTMODE == 1) {
                #pragma unroll
                for (int r = 0; r < 4; ++r)
                    ofp[(size_t)(blockrow + t*64 + wid*16 + kg*4 + r) * CO + dcol] = v[r];
            } else {
                float mx = fmaxf(fmaxf(v[0], v[1]), fmaxf(v[2], v[3]));
                mx = fmaxf(mx, __shfl_xor(mx, 16));
                mx = fmaxf(mx, __shfl_xor(mx, 32));
                if (lane < 16) partial[wid][t][nt*16 + m] = mx;
            }
        }
    }
    if constexpr (OUTMODE == 2) {
        __syncthreads();
        for (int c = threadIdx.x; c < 16*NTILE; c += 256) {
            #pragma unroll
            for (int t = 0; t < MROW; ++t) {
                if constexpr (KPTS == 64) {
                    float mx = fmaxf(fmaxf(partial[0][t][c], partial[1][t][c]),
                                     fmaxf(partial[2][t][c], partial[3][t][c]));
                    int cent = (rowbase + blockrow) / 64 + t;
                    ofp[(size_t)cent*CO + colbase + c] = mx;
                } else {               // KPTS == 32: each 16-row pair is a centroid half
                    int cent0 = (rowbase + blockrow) / 32 + t*2;
                    ofp[(size_t)cent0*CO + colbase + c]     = fmaxf(partial[0][t][c], partial[1][t][c]);
                    ofp[(size_t)(cent0+1)*CO + colbase + c] = fmaxf(partial[2][t][c], partial[3][t][c]);
                }
            }
        }
    }
}

// ---------------------------------------------------------------------------
// concat [R,3] ++ [R,CF] -> [R,3+CF]
// ---------------------------------------------------------------------------
__global__ void concat_kernel(const float* __restrict__ a, const float* __restrict__ f,
                              float* __restrict__ out, int R, int CF)
{
    int C = CF + 3;
    int t = blockIdx.x * blockDim.x + threadIdx.x;
    if (t >= R * C) return;
    int r = t / C, c = t % C;
    out[t] = (c < 3) ? a[r*3 + c] : f[(size_t)r * CF + (c - 3)];
}

// ---------------------------------------------------------------------------
// Tiled fp32 GEMM, 64x64 tile / 4x4 micro (K=259 layer + FC head).
// ---------------------------------------------------------------------------
template<int RELU, int HASB>
__global__ __launch_bounds__(256) void gemm_kernel(
    const float* __restrict__ A, const float* __restrict__ W,
    const float* __restrict__ bias, float* __restrict__ Cc,
    int Mr, int Nc, int Kd)
{
    __shared__ float As[64][17];
    __shared__ float Ws[16][65];
    int tx = threadIdx.x % 16;
    int ty = threadIdx.x / 16;
    int row0 = blockIdx.y * 64;
    int col0 = blockIdx.x * 64;
    float acc[4][4] = {};
    for (int k0 = 0; k0 < Kd; k0 += 16) {
        for (int t = threadIdx.x; t < 64*16; t += 256) {
            int r = t >> 4, kk = t & 15;
            int gr = row0 + r, gk = k0 + kk;
            As[r][kk] = (gr < Mr && gk < Kd) ? A[(size_t)gr * Kd + gk] : 0.f;
        }
        for (int t = threadIdx.x; t < 16*64; t += 256) {
            int kk = t >> 6, c = t & 63;
            int gk = k0 + kk, gc = col0 + c;
            Ws[kk][c] = (gk < Kd && gc < Nc) ? W[(size_t)gk * Nc + gc] : 0.f;
        }
        __syncthreads();
        #pragma unroll
        for (int kk = 0; kk < 16; ++kk) {
            float av[4], wv[4];
            #pragma unroll
            for (int i = 0; i < 4; i++) av[i] = As[ty*4+i][kk];
            #pragma unroll
            for (int j = 0; j < 4; j++) wv[j] = Ws[kk][tx*4+j];
            #pragma unroll
            for (int i = 0; i < 4; i++)
                #pragma unroll
                for (int j = 0; j < 4; j++)
                    acc[i][j] += av[i] * wv[j];
        }
        __syncthreads();
    }
    #pragma unroll
    for (int i = 0; i < 4; i++) {
        int gr = row0 + ty*4 + i;
        if (gr >= Mr) continue;
        #pragma unroll
        for (int j = 0; j < 4; j++) {
            int gc = col0 + tx*4 + j;
            if (gc >= Nc) continue;
            float v = acc[i][j];
            if (HASB) v += bias[gc];
            if (RELU) v = fmaxf(v, 0.f);
            Cc[(size_t)gr * Nc + gc] = v;
        }
    }
}

// ---------------------------------------------------------------------------
// Max over P points: in [B,P,C] -> out [B,C]
// ---------------------------------------------------------------------------
__global__ void rowmax_kernel(const float* __restrict__ in, float* __restrict__ out,
                              int B, int P, int C)
{
    int t = blockIdx.x * blockDim.x + threadIdx.x;
    if (t >= B * C) return;
    int b = t / C, c = t % C;
    const float* p = in + (size_t)b * P * C + c;
    float mx = p[0];
    for (int i = 1; i < P; ++i) mx = fmaxf(mx, p[(size_t)i * C]);
    out[t] = mx;
}

// ---------------------------------------------------------------------------
extern "C" void kernel_launch(void* const* d_in, const int* in_sizes, int n_in,
                              void* d_out, int out_size, void* d_ws, size_t ws_size,
                              hipStream_t stream)
{
    const float* xyz    = (const float*)d_in[0];
    const float* points = (const float*)d_in[1];
    const float* w1a = (const float*)d_in[2];  const float* b1a = (const float*)d_in[3];
    const float* w1b = (const float*)d_in[4];  const float* b1b = (const float*)d_in[5];
    const float* w1c = (const float*)d_in[6];  const float* b1c = (const float*)d_in[7];
    const float* w2a = (const float*)d_in[8];  const float* b2a = (const float*)d_in[9];
    const float* w2b = (const float*)d_in[10]; const float* b2b = (const float*)d_in[11];
    const float* w2c = (const float*)d_in[12]; const float* b2c = (const float*)d_in[13];
    const float* w3a = (const float*)d_in[14]; const float* b3a = (const float*)d_in[15];
    const float* w3b = (const float*)d_in[16]; const float* b3b = (const float*)d_in[17];
    const float* w3c = (const float*)d_in[18]; const float* b3c = (const float*)d_in[19];
    const float* lin1 = (const float*)d_in[20];
    const float* lin2 = (const float*)d_in[21];
    const float* clsw = (const float*)d_in[22];
    const float* clsb = (const float*)d_in[23];

    char* ws = (char*)d_ws;
    size_t off = 0;
    auto alloc = [&](size_t bytes) -> void* {
        void* p = ws + off;
        off += (bytes + 255) & ~(size_t)255;
        return p;
    };
    int*   fps1 = (int*)  alloc((size_t)32*512*4);
    float* nx1  = (float*)alloc((size_t)32*512*3*4);
    int*   gi1  = (int*)  alloc((size_t)32*512*32*4);
    float* f1   = (float*)alloc((size_t)32*512*128*4);
    int*   fps2 = (int*)  alloc((size_t)32*128*4);
    float* nx2  = (float*)alloc((size_t)32*128*3*4);
    int*   gi2  = (int*)  alloc((size_t)32*128*64*4);
    float* f2   = (float*)alloc((size_t)32*128*256*4);
    float* g3   = (float*)alloc((size_t)4096*259*4);
    float* h3a  = (float*)alloc((size_t)4096*256*4);
    float* h3c  = (float*)alloc((size_t)4096*1024*4);
    float* f3   = (float*)alloc((size_t)32*1024*4);
    float* fc1  = (float*)alloc((size_t)32*512*4);
    float* fc2  = (float*)alloc((size_t)32*256*4);

    typedef unsigned short us;
    // split weights (transposed [CO][CI], bf16 hi/lo)
    us* w1bh = (us*)alloc(64*64*2);     us* w1bl = (us*)alloc(64*64*2);
    us* w1ch = (us*)alloc(128*64*2);    us* w1cl = (us*)alloc(128*64*2);
    us* w2bh = (us*)alloc(128*128*2);   us* w2bl = (us*)alloc(128*128*2);
    us* w2ch = (us*)alloc(256*128*2);   us* w2cl = (us*)alloc(256*128*2);
    us* w3bh = (us*)alloc(512*256*2);   us* w3bl = (us*)alloc(512*256*2);
    us* w3ch = (us*)alloc(1024*512*2);  us* w3cl = (us*)alloc(1024*512*2);
    // split SA3 activations
    us* h3aH = (us*)alloc((size_t)4096*256*2);  us* h3aL = (us*)alloc((size_t)4096*256*2);
    us* h3bH = (us*)alloc((size_t)4096*512*2);  us* h3bL = (us*)alloc((size_t)4096*512*2);

    // big split activation ping-pong buffers (hi/lo per side)
    size_t avail = (ws_size > off + 1024) ? (ws_size - off - 1024) : 0;
    size_t bufcap = avail / 4;
    if (bufcap > (size_t)67200000) bufcap = 67200000;   // 524288 rows x 64ch x 2B
    us* Ah = (us*)alloc(bufcap); us* Al = (us*)alloc(bufcap);
    us* Bh = (us*)alloc(bufcap); us* Bl = (us*)alloc(bufcap);

    // ---- weight prep (independent of data flow)
    auto wsp = [&](const float* w, int CI, int CO, us* wh, us* wl) {
        wsplit_kernel<<<ceil_div(CI*CO, 256), 256, 0, stream>>>(w, wh, wl, CI, CO);
    };
    wsp(w1b, 64, 64,  w1bh, w1bl);
    wsp(w1c, 64, 128, w1ch, w1cl);
    wsp(w2b, 128, 128, w2bh, w2bl);
    wsp(w2c, 128, 256, w2ch, w2cl);
    wsp(w3b, 256, 512, w3bh, w3bl);
    wsp(w3c, 512, 1024, w3ch, w3cl);

    // ---- SA1: N=1024 -> M=512, r=0.2, K=32, MLP 6->64->64->128
    fps_kernel<1024><<<32, 64, 0, stream>>>(xyz, 512, fps1, nx1);
    ballquery_kernel<<<ceil_div(32*512, 256), 256, 0, stream>>>(
        xyz, nx1, gi1, 32, 1024, 512, 32, (float)(0.2*0.2));
    {
        const int rows = 32*512*32;                     // 524288
        int ch = (int)((bufcap / (64*2)) & ~(size_t)255);
        if (ch > rows) ch = rows;
        if (ch < 256) ch = 256;
        for (int r0 = 0; r0 < rows; r0 += ch) {
            int rc = rows - r0 < ch ? rows - r0 : ch;
            sa_l1_kernel<3, 64, 32><<<rc/64, 256, 0, stream>>>(
                xyz, points, nx1, gi1, w1a, b1a, Ah, Al, 1024, 512, r0);
            mfma_layer_kernel<64, 64, 4, 4, 0, 0><<<dim3(rc/256, 1), 256, 0, stream>>>(
                Ah, Al, w1bh, w1bl, b1b, Bh, Bl, nullptr, 0);
            mfma_layer_kernel<64, 128, 8, 4, 32, 2><<<dim3(rc/256, 1), 256, 0, stream>>>(
                Bh, Bl, w1ch, w1cl, b1c, nullptr, nullptr, f1, r0);
        }
    }

    // ---- SA2: N=512 -> M=128, r=0.4, K=64, MLP 131->128->128->256
    fps_kernel<512><<<32, 64, 0, stream>>>(nx1, 128, fps2, nx2);
    ballquery_kernel<<<ceil_div(32*128, 256), 256, 0, stream>>>(
        nx1, nx2, gi2, 32, 512, 128, 64, (float)(0.4*0.4));
    {
        const int rows = 32*128*64;                     // 262144
        int ch = (int)((bufcap / (128*2)) & ~(size_t)255);
        if (ch > rows) ch = rows;
        if (ch < 256) ch = 256;
        for (int r0 = 0; r0 < rows; r0 += ch) {
            int rc = rows - r0 < ch ? rows - r0 : ch;
            sa_l1_kernel<128, 128, 64><<<rc/64, 256, 0, stream>>>(
                nx1, f1, nx2, gi2, w2a, b2a, Ah, Al, 512, 128, r0);
            mfma_layer_kernel<128, 128, 8, 4, 0, 0><<<dim3(rc/256, 1), 256, 0, stream>>>(
                Ah, Al, w2bh, w2bl, b2b, Bh, Bl, nullptr, 0);
            mfma_layer_kernel<128, 256, 16, 4, 64, 2><<<dim3(rc/256, 1), 256, 0, stream>>>(
                Bh, Bl, w2ch, w2cl, b2c, nullptr, nullptr, f2, r0);
        }
    }

    // ---- SA3 (group_all): concat [4096,259] -> 259->256 (fp32 gemm) ->
    //      256->512 (mfma) -> 512->1024 (mfma) -> max over 128
    concat_kernel<<<ceil_div(4096*259, 256), 256, 0, stream>>>(nx2, f2, g3, 4096, 256);
    {
        dim3 g(ceil_div(256, 64), ceil_div(4096, 64));
        gemm_kernel<1,1><<<g, 256, 0, stream>>>(g3, w3a, b3a, h3a, 4096, 256, 259);
    }
    asplit_kernel<<<ceil_div(4096*256, 256), 256, 0, stream>>>(h3a, h3aH, h3aL, 4096*256);
    // 256->512: NTILE=2, MROW=2 -> grid (32, 16) = 512 blocks.
    mfma_layer_kernel<256, 512, 2, 2, 0, 0><<<dim3(4096/128, 512/32), 256, 0, stream>>>(
        h3aH, h3aL, w3bh, w3bl, b3b, h3bH, h3bL, nullptr, 0);
    // 512->1024: NTILE=4, MROW=1 -> grid (64, 16) = 1024 blocks.
    mfma_layer_kernel<512, 1024, 4, 1, 0, 1><<<dim3(4096/64, 1024/64), 256, 0, stream>>>(
        h3bH, h3bL, w3ch, w3cl, b3c, nullptr, nullptr, h3c, 0);
    rowmax_kernel<<<ceil_div(32*1024, 256), 256, 0, stream>>>(h3c, f3, 32, 128, 1024);

    // ---- FC head (fp32)
    {
        dim3 g(ceil_div(512, 64), 1);
        gemm_kernel<1,0><<<g, 256, 0, stream>>>(f3, lin1, nullptr, fc1, 32, 512, 1024);
    }
    {
        dim3 g(ceil_div(256, 64), 1);
        gemm_kernel<1,0><<<g, 256, 0, stream>>>(fc1, lin2, nullptr, fc2, 32, 256, 512);
    }
    {
        dim3 g(1, 1);
        gemm_kernel<0,1><<<g, 256, 0, stream>>>(fc2, clsw, clsb, (float*)d_out, 32, 40, 256);
    }
}

// Round 15
// 1340.298 us; speedup vs baseline: 1.8368x; 1.1856x over previous
//
#include <hip/hip_runtime.h>

#define DEVFN __device__ __forceinline__

static inline int ceil_div(int a, int b) { return (a + b - 1) / b; }

typedef __attribute__((ext_vector_type(8))) short         bf16x8;  // 8 bf16 = 4 VGPR
typedef __attribute__((ext_vector_type(4))) float         f32x4;
typedef __attribute__((ext_vector_type(8))) unsigned short u16x8;

DEVFN unsigned short f2bf(float x) {           // RNE float->bf16 (finite inputs)
    unsigned u = __float_as_uint(x);
    unsigned r = ((u >> 16) & 1u) + 0x7fffu;
    return (unsigned short)((u + r) >> 16);
}
DEVFN float bf2f(unsigned short h) { return __uint_as_float(((unsigned)h) << 16); }

// ---------------------------------------------------------------------------
// DPP-based 64-lane max reduction step for a packed double key.
// ---------------------------------------------------------------------------
template<int CTRL>
DEVFN double dpp_max_step(double v)
{
    int lo = __double2loint(v), hi = __double2hiint(v);
    int tlo = __builtin_amdgcn_update_dpp(lo, lo, CTRL, 0xF, 0xF, false);
    int thi = __builtin_amdgcn_update_dpp(hi, hi, CTRL, 0xF, 0xF, false);
    return fmax(v, __hiloint2double(thi, tlo));
}

// ---------------------------------------------------------------------------
// Farthest point sampling — SINGLE WAVE per batch, packed-key argmax with
// 6-step DPP max reduce (unchanged; 202 µs @ N=1024).
// ---------------------------------------------------------------------------
template<int N>
__global__ __launch_bounds__(64) void fps_kernel(const float* __restrict__ xyz, int M,
                                                 int* __restrict__ out_idx,
                                                 float* __restrict__ nxout)
{
    constexpr int PPL = N / 64;
    int b = blockIdx.x, lane = threadIdx.x;
    __shared__ float4 sp[N];
    const float* p = xyz + (size_t)b * N * 3;
    float px[PPL], py[PPL], pz[PPL], dd[PPL];
    unsigned lo[PPL];
    #pragma unroll
    for (int j = 0; j < PPL; ++j) {
        int idx = lane + 64 * j;
        px[j] = p[idx*3+0]; py[j] = p[idx*3+1]; pz[j] = p[idx*3+2];
        sp[idx] = make_float4(px[j], py[j], pz[j], 0.f);
        dd[j] = 1e10f;
        lo[j] = ~(unsigned)idx;
    }
    __syncthreads();
    int far = 0;
    for (int s = 0; s < M; ++s) {
        float4 c4 = sp[far];
        if (lane == 0) {
            out_idx[(size_t)b*M + s] = far;
            nxout[((size_t)b*M + s)*3 + 0] = c4.x;
            nxout[((size_t)b*M + s)*3 + 1] = c4.y;
            nxout[((size_t)b*M + s)*3 + 2] = c4.z;
        }
        double cand[PPL];
        #pragma unroll
        for (int j = 0; j < PPL; ++j) {
            float dx = __fsub_rn(px[j], c4.x);
            float dy = __fsub_rn(py[j], c4.y);
            float dz = __fsub_rn(pz[j], c4.z);
            float d  = __fadd_rn(__fadd_rn(__fmul_rn(dx,dx), __fmul_rn(dy,dy)),
                                 __fmul_rn(dz,dz));
            float nd = fminf(dd[j], d);
            dd[j] = nd;
            cand[j] = __hiloint2double(__float_as_int(nd), (int)lo[j]);
        }
        #pragma unroll
        for (int st = PPL/2; st > 0; st >>= 1)
            #pragma unroll
            for (int j = 0; j < PPL; ++j)
                if (j < st) cand[j] = fmax(cand[j], cand[j + st]);
        double v = cand[0];
        v = dpp_max_step<0xB1>(v);
        v = dpp_max_step<0x4E>(v);
        v = dpp_max_step<0x124>(v);
        v = dpp_max_step<0x128>(v);
        v = dpp_max_step<0x142>(v);
        v = dpp_max_step<0x143>(v);
        int wlo = __builtin_amdgcn_readlane(__double2loint(v), 63);
        far = (int)(~(unsigned)wlo);
    }
}

// ---------------------------------------------------------------------------
// Ball query (unchanged).
// ---------------------------------------------------------------------------
__global__ void ballquery_kernel(const float* __restrict__ xyz,
                                 const float* __restrict__ new_xyz,
                                 int* __restrict__ gi,
                                 int B, int N, int M, int K, float r2)
{
    int t = blockIdx.x * blockDim.x + threadIdx.x;
    if (t >= B * M) return;
    int b = t / M;
    const float* p = xyz + (size_t)b * N * 3;
    float cx = new_xyz[t*3+0], cy = new_xyz[t*3+1], cz = new_xyz[t*3+2];
    int* out = gi + (size_t)t * K;
    int cnt = 0, first = 0;
    bool havefirst = false;
    for (int i = 0; i < N; ++i) {
        float dx = __fsub_rn(p[i*3+0], cx);
        float dy = __fsub_rn(p[i*3+1], cy);
        float dz = __fsub_rn(p[i*3+2], cz);
        float d  = __fadd_rn(__fadd_rn(__fmul_rn(dx,dx), __fmul_rn(dy,dy)),
                             __fmul_rn(dz,dz));
        if (d <= r2) {
            if (!havefirst) { first = i; havefirst = true; }
            out[cnt++] = i;
            if (cnt == K) break;
        }
    }
    for (; cnt < K; ++cnt) out[cnt] = first;
}

DEVFN float f4_elem(const float4& v, int u) {
    return u == 0 ? v.x : u == 1 ? v.y : u == 2 ? v.z : v.w;
}

// ---------------------------------------------------------------------------
// Weight split+transpose prep: w [CI][CO] fp32 -> wh/wl [CO][CI] bf16 pair.
// ---------------------------------------------------------------------------
__global__ void wsplit_kernel(const float* __restrict__ w,
                              unsigned short* __restrict__ wh,
                              unsigned short* __restrict__ wl, int CI, int CO)
{
    int t = blockIdx.x * 256 + threadIdx.x;
    if (t >= CI * CO) return;
    int co = t / CI, ci = t % CI;
    float v = w[(size_t)ci * CO + co];
    unsigned short h = f2bf(v);
    wh[t] = h;
    wl[t] = f2bf(v - bf2f(h));
}

// Elementwise fp32 -> split bf16 pair (same layout).
__global__ void asplit_kernel(const float* __restrict__ a,
                              unsigned short* __restrict__ ah,
                              unsigned short* __restrict__ al, int n)
{
    int t = blockIdx.x * 256 + threadIdx.x;
    if (t >= n) return;
    float v = a[t];
    unsigned short h = f2bf(v);
    ah[t] = h;
    al[t] = f2bf(v - bf2f(h));
}

// ---------------------------------------------------------------------------
// SA layer 1 (fused gather + centering), fp32 VALU, writing ROW-MAJOR
// split-bf16 activations for the MFMA layers (unchanged from R12).
// ---------------------------------------------------------------------------
template<int CF, int CO, int KPTS>
__global__ __launch_bounds__(256) void sa_l1_kernel(
    const float* __restrict__ xyz, const float* __restrict__ feats,
    const float* __restrict__ new_xyz, const int* __restrict__ gi,
    const float* __restrict__ w, const float* __restrict__ bias,
    unsigned short* __restrict__ oh, unsigned short* __restrict__ ol,
    int N, int M, int row0)
{
    constexpr int WCH = CO / 4;
    const int lane = threadIdx.x & 63;
    const int wv   = __builtin_amdgcn_readfirstlane(threadIdx.x >> 6);
    const int rl   = blockIdx.x * 64 + lane;
    const int row  = row0 + rl;
    const int cent = row / KPTS;
    const int b    = cent / M;
    const int idx  = gi[row];
    const float* pp  = xyz + ((size_t)b*N + idx)*3;
    const float* cc3 = new_xyz + (size_t)cent*3;
    float a0 = __fsub_rn(pp[0], cc3[0]);
    float a1 = __fsub_rn(pp[1], cc3[1]);
    float a2 = __fsub_rn(pp[2], cc3[2]);
    const float* frow = feats + ((size_t)b*N + idx)*CF;
    const float* wcol = w + wv*WCH;
    const float* bcol = bias + wv*WCH;
    float acc[WCH];
    #pragma unroll
    for (int j = 0; j < WCH; ++j) acc[j] = bcol[j];
    #pragma unroll
    for (int j = 0; j < WCH; ++j) acc[j] += a0 * wcol[0*CO + j];
    #pragma unroll
    for (int j = 0; j < WCH; ++j) acc[j] += a1 * wcol[1*CO + j];
    #pragma unroll
    for (int j = 0; j < WCH; ++j) acc[j] += a2 * wcol[2*CO + j];
    constexpr int CF4 = CF & ~3;
    #pragma unroll 2
    for (int cc = 0; cc < CF4; cc += 4) {
        float4 a4 = *(const float4*)(frow + cc);
        #pragma unroll
        for (int u = 0; u < 4; ++u) {
            float a = f4_elem(a4, u);
            #pragma unroll
            for (int j = 0; j < WCH; ++j)
                acc[j] += a * wcol[(size_t)(3 + cc + u)*CO + j];
        }
    }
    #pragma unroll
    for (int f = CF4; f < CF; ++f) {
        float a = frow[f];
        #pragma unroll
        for (int j = 0; j < WCH; ++j)
            acc[j] += a * wcol[(size_t)(3 + f)*CO + j];
    }
    #pragma unroll
    for (int j8 = 0; j8 < WCH; j8 += 8) {
        u16x8 hv, lv;
        #pragma unroll
        for (int u = 0; u < 8; ++u) {
            float v = fmaxf(acc[j8+u], 0.f);
            unsigned short h = f2bf(v);
            hv[u] = (unsigned short)h;
            lv[u] = f2bf(v - bf2f(h));
        }
        size_t o = (size_t)rl*CO + wv*WCH + j8;
        *(u16x8*)(&oh[o]) = hv;
        *(u16x8*)(&ol[o]) = lv;
    }
}

// ---------------------------------------------------------------------------
// MFMA layer with column tiling + MROW row-tiles per wave (unchanged R14).
// OUTMODE: 0 = split-bf16 out, 1 = fp32 row-major out, 2 = maxpool(KPTS)->fp32
// ---------------------------------------------------------------------------
template<int CI, int CO, int NTILE, int MROW, int KPTS, int OUTMODE>
__global__ __launch_bounds__(256) void mfma_layer_kernel(
    const unsigned short* __restrict__ ah, const unsigned short* __restrict__ al,
    const unsigned short* __restrict__ wh, const unsigned short* __restrict__ wl,
    const float* __restrict__ bias,
    unsigned short* __restrict__ oh, unsigned short* __restrict__ ol,
    float* __restrict__ ofp, int rowbase)
{
    constexpr int KT = CI / 32;
    static_assert(KT * MROW <= 16, "A-preload register budget");
    __shared__ float partial[4][OUTMODE == 2 ? MROW : 1][OUTMODE == 2 ? 16*NTILE : 1];
    const int wid  = threadIdx.x >> 6;
    const int lane = threadIdx.x & 63;
    const int m    = lane & 15;
    const int kg   = lane >> 4;
    const int blockrow = blockIdx.x * (64 * MROW);
    const int colbase  = blockIdx.y * (16 * NTILE);
    bf16x8 Ahf[MROW * KT], Alf[MROW * KT];
    #pragma unroll
    for (int t = 0; t < MROW; ++t) {
        const unsigned short* arh =
            ah + (size_t)(blockrow + t*64 + wid*16 + m) * CI + kg * 8;
        const unsigned short* arl =
            al + (size_t)(blockrow + t*64 + wid*16 + m) * CI + kg * 8;
        #pragma unroll
        for (int kt = 0; kt < KT; ++kt) {
            Ahf[t*KT + kt] = *(const bf16x8*)(arh + kt*32);
            Alf[t*KT + kt] = *(const bf16x8*)(arl + kt*32);
        }
    }
    #pragma unroll
    for (int nt = 0; nt < NTILE; ++nt) {
        f32x4 acc[MROW];
        #pragma unroll
        for (int t = 0; t < MROW; ++t) acc[t] = (f32x4){0.f, 0.f, 0.f, 0.f};
        const unsigned short* wbh = wh + (size_t)(colbase + nt*16 + m) * CI + kg * 8;
        const unsigned short* wbl = wl + (size_t)(colbase + nt*16 + m) * CI + kg * 8;
        #pragma unroll
        for (int kt = 0; kt < KT; ++kt) {
            bf16x8 Bh = *(const bf16x8*)(wbh + kt*32);
            bf16x8 Bl = *(const bf16x8*)(wbl + kt*32);
            #pragma unroll
            for (int t = 0; t < MROW; ++t) {
                acc[t] = __builtin_amdgcn_mfma_f32_16x16x32_bf16(Ahf[t*KT+kt], Bh, acc[t], 0, 0, 0);
                acc[t] = __builtin_amdgcn_mfma_f32_16x16x32_bf16(Ahf[t*KT+kt], Bl, acc[t], 0, 0, 0);
                acc[t] = __builtin_amdgcn_mfma_f32_16x16x32_bf16(Alf[t*KT+kt], Bh, acc[t], 0, 0, 0);
            }
        }
        int dcol = colbase + nt*16 + m;
        float bv = bias[dcol];
        #pragma unroll
        for (int t = 0; t < MROW; ++t) {
            float v[4];
            #pragma unroll
            for (int r = 0; r < 4; ++r) v[r] = fmaxf(acc[t][r] + bv, 0.f);
            if constexpr (OUTMODE == 0) {
                #pragma unroll
                for (int r = 0; r < 4; ++r) {
                    size_t o = (size_t)(blockrow + t*64 + wid*16 + kg*4 + r) * CO + dcol;
                    unsigned short h = f2bf(v[r]);
                    oh[o] = h;
                    ol[o] = f2bf(v[r] - bf2f(h));
                }
            } else if constexpr (OUTMODE == 1) {
                #pragma unroll
                for (int r = 0; r < 4; ++r)
                    ofp[(size_t)(blockrow + t*64 + wid*16 + kg*4 + r) * CO + dcol] = v[r];
            } else {
                float mx = fmaxf(fmaxf(v[0], v[1]), fmaxf(v[2], v[3]));
                mx = fmaxf(mx, __shfl_xor(mx, 16));
                mx = fmaxf(mx, __shfl_xor(mx, 32));
                if (lane < 16) partial[wid][t][nt*16 + m] = mx;
            }
        }
    }
    if constexpr (OUTMODE == 2) {
        __syncthreads();
        for (int c = threadIdx.x; c < 16*NTILE; c += 256) {
            #pragma unroll
            for (int t = 0; t < MROW; ++t) {
                if constexpr (KPTS == 64) {
                    float mx = fmaxf(fmaxf(partial[0][t][c], partial[1][t][c]),
                                     fmaxf(partial[2][t][c], partial[3][t][c]));
                    int cent = (rowbase + blockrow) / 64 + t;
                    ofp[(size_t)cent*CO + colbase + c] = mx;
                } else {               // KPTS == 32: each 16-row pair is a centroid half
                    int cent0 = (rowbase + blockrow) / 32 + t*2;
                    ofp[(size_t)cent0*CO + colbase + c]     = fmaxf(partial[0][t][c], partial[1][t][c]);
                    ofp[(size_t)(cent0+1)*CO + colbase + c] = fmaxf(partial[2][t][c], partial[3][t][c]);
                }
            }
        }
    }
}

// ---------------------------------------------------------------------------
// concat [R,3] ++ [R,CF] -> [R,3+CF]
// ---------------------------------------------------------------------------
__global__ void concat_kernel(const float* __restrict__ a, const float* __restrict__ f,
                              float* __restrict__ out, int R, int CF)
{
    int C = CF + 3;
    int t = blockIdx.x * blockDim.x + threadIdx.x;
    if (t >= R * C) return;
    int r = t / C, c = t % C;
    out[t] = (c < 3) ? a[r*3 + c] : f[(size_t)r * CF + (c - 3)];
}

// ---------------------------------------------------------------------------
// Tiled fp32 GEMM, 64x64 tile / 4x4 micro (SA3 K=259 layer only).
// ---------------------------------------------------------------------------
template<int RELU, int HASB>
__global__ __launch_bounds__(256) void gemm_kernel(
    const float* __restrict__ A, const float* __restrict__ W,
    const float* __restrict__ bias, float* __restrict__ Cc,
    int Mr, int Nc, int Kd)
{
    __shared__ float As[64][17];
    __shared__ float Ws[16][65];
    int tx = threadIdx.x % 16;
    int ty = threadIdx.x / 16;
    int row0 = blockIdx.y * 64;
    int col0 = blockIdx.x * 64;
    float acc[4][4] = {};
    for (int k0 = 0; k0 < Kd; k0 += 16) {
        for (int t = threadIdx.x; t < 64*16; t += 256) {
            int r = t >> 4, kk = t & 15;
            int gr = row0 + r, gk = k0 + kk;
            As[r][kk] = (gr < Mr && gk < Kd) ? A[(size_t)gr * Kd + gk] : 0.f;
        }
        for (int t = threadIdx.x; t < 16*64; t += 256) {
            int kk = t >> 6, c = t & 63;
            int gk = k0 + kk, gc = col0 + c;
            Ws[kk][c] = (gk < Kd && gc < Nc) ? W[(size_t)gk * Nc + gc] : 0.f;
        }
        __syncthreads();
        #pragma unroll
        for (int kk = 0; kk < 16; ++kk) {
            float av[4], wv[4];
            #pragma unroll
            for (int i = 0; i < 4; i++) av[i] = As[ty*4+i][kk];
            #pragma unroll
            for (int j = 0; j < 4; j++) wv[j] = Ws[kk][tx*4+j];
            #pragma unroll
            for (int i = 0; i < 4; i++)
                #pragma unroll
                for (int j = 0; j < 4; j++)
                    acc[i][j] += av[i] * wv[j];
        }
        __syncthreads();
    }
    #pragma unroll
    for (int i = 0; i < 4; i++) {
        int gr = row0 + ty*4 + i;
        if (gr >= Mr) continue;
        #pragma unroll
        for (int j = 0; j < 4; j++) {
            int gc = col0 + tx*4 + j;
            if (gc >= Nc) continue;
            float v = acc[i][j];
            if (HASB) v += bias[gc];
            if (RELU) v = fmaxf(v, 0.f);
            Cc[(size_t)gr * Nc + gc] = v;
        }
    }
}

// ---------------------------------------------------------------------------
// Small-M FC GEMM: one thread per output element, no LDS, no barriers.
// W reads coalesce across lanes; A row reads are wave-uniform broadcasts.
// k ascending + bias-after-loop == gemm_kernel's order (bitwise identical).
// ---------------------------------------------------------------------------
template<int RELU, int HASB>
__global__ __launch_bounds__(256) void fc_kernel(
    const float* __restrict__ A, const float* __restrict__ W,
    const float* __restrict__ bias, float* __restrict__ Cc,
    int Mr, int Nc, int Kd)
{
    int t = blockIdx.x * 256 + threadIdx.x;
    if (t >= Mr * Nc) return;
    int row = t / Nc, col = t % Nc;
    const float* a = A + (size_t)row * Kd;
    const float* w = W + col;
    float acc = 0.f;
    #pragma unroll 8
    for (int k = 0; k < Kd; ++k)
        acc += a[k] * w[(size_t)k * Nc];
    if (HASB) acc += bias[col];
    if (RELU) acc = fmaxf(acc, 0.f);
    Cc[t] = acc;
}

// ---------------------------------------------------------------------------
// Max over P points: in [B,P,C] -> out [B,C]
// ---------------------------------------------------------------------------
__global__ void rowmax_kernel(const float* __restrict__ in, float* __restrict__ out,
                              int B, int P, int C)
{
    int t = blockIdx.x * blockDim.x + threadIdx.x;
    if (t >= B * C) return;
    int b = t / C, c = t % C;
    const float* p = in + (size_t)b * P * C + c;
    float mx = p[0];
    for (int i = 1; i < P; ++i) mx = fmaxf(mx, p[(size_t)i * C]);
    out[t] = mx;
}

// ---------------------------------------------------------------------------
extern "C" void kernel_launch(void* const* d_in, const int* in_sizes, int n_in,
                              void* d_out, int out_size, void* d_ws, size_t ws_size,
                              hipStream_t stream)
{
    const float* xyz    = (const float*)d_in[0];
    const float* points = (const float*)d_in[1];
    const float* w1a = (const float*)d_in[2];  const float* b1a = (const float*)d_in[3];
    const float* w1b = (const float*)d_in[4];  const float* b1b = (const float*)d_in[5];
    const float* w1c = (const float*)d_in[6];  const float* b1c = (const float*)d_in[7];
    const float* w2a = (const float*)d_in[8];  const float* b2a = (const float*)d_in[9];
    const float* w2b = (const float*)d_in[10]; const float* b2b = (const float*)d_in[11];
    const float* w2c = (const float*)d_in[12]; const float* b2c = (const float*)d_in[13];
    const float* w3a = (const float*)d_in[14]; const float* b3a = (const float*)d_in[15];
    const float* w3b = (const float*)d_in[16]; const float* b3b = (const float*)d_in[17];
    const float* w3c = (const float*)d_in[18]; const float* b3c = (const float*)d_in[19];
    const float* lin1 = (const float*)d_in[20];
    const float* lin2 = (const float*)d_in[21];
    const float* clsw = (const float*)d_in[22];
    const float* clsb = (const float*)d_in[23];

    char* ws = (char*)d_ws;
    size_t off = 0;
    auto alloc = [&](size_t bytes) -> void* {
        void* p = ws + off;
        off += (bytes + 255) & ~(size_t)255;
        return p;
    };
    int*   fps1 = (int*)  alloc((size_t)32*512*4);
    float* nx1  = (float*)alloc((size_t)32*512*3*4);
    int*   gi1  = (int*)  alloc((size_t)32*512*32*4);
    float* f1   = (float*)alloc((size_t)32*512*128*4);
    int*   fps2 = (int*)  alloc((size_t)32*128*4);
    float* nx2  = (float*)alloc((size_t)32*128*3*4);
    int*   gi2  = (int*)  alloc((size_t)32*128*64*4);
    float* f2   = (float*)alloc((size_t)32*128*256*4);
    float* g3   = (float*)alloc((size_t)4096*259*4);
    float* h3a  = (float*)alloc((size_t)4096*256*4);
    float* h3c  = (float*)alloc((size_t)4096*1024*4);
    float* f3   = (float*)alloc((size_t)32*1024*4);
    float* fc1  = (float*)alloc((size_t)32*512*4);
    float* fc2  = (float*)alloc((size_t)32*256*4);

    typedef unsigned short us;
    // split weights (transposed [CO][CI], bf16 hi/lo)
    us* w1bh = (us*)alloc(64*64*2);     us* w1bl = (us*)alloc(64*64*2);
    us* w1ch = (us*)alloc(128*64*2);    us* w1cl = (us*)alloc(128*64*2);
    us* w2bh = (us*)alloc(128*128*2);   us* w2bl = (us*)alloc(128*128*2);
    us* w2ch = (us*)alloc(256*128*2);   us* w2cl = (us*)alloc(256*128*2);
    us* w3bh = (us*)alloc(512*256*2);   us* w3bl = (us*)alloc(512*256*2);
    us* w3ch = (us*)alloc(1024*512*2);  us* w3cl = (us*)alloc(1024*512*2);
    // split SA3 activations
    us* h3aH = (us*)alloc((size_t)4096*256*2);  us* h3aL = (us*)alloc((size_t)4096*256*2);
    us* h3bH = (us*)alloc((size_t)4096*512*2);  us* h3bL = (us*)alloc((size_t)4096*512*2);

    // big split activation ping-pong buffers (hi/lo per side)
    size_t avail = (ws_size > off + 1024) ? (ws_size - off - 1024) : 0;
    size_t bufcap = avail / 4;
    if (bufcap > (size_t)67200000) bufcap = 67200000;   // 524288 rows x 64ch x 2B
    us* Ah = (us*)alloc(bufcap); us* Al = (us*)alloc(bufcap);
    us* Bh = (us*)alloc(bufcap); us* Bl = (us*)alloc(bufcap);

    // ---- weight prep (independent of data flow)
    auto wsp = [&](const float* w, int CI, int CO, us* wh, us* wl) {
        wsplit_kernel<<<ceil_div(CI*CO, 256), 256, 0, stream>>>(w, wh, wl, CI, CO);
    };
    wsp(w1b, 64, 64,  w1bh, w1bl);
    wsp(w1c, 64, 128, w1ch, w1cl);
    wsp(w2b, 128, 128, w2bh, w2bl);
    wsp(w2c, 128, 256, w2ch, w2cl);
    wsp(w3b, 256, 512, w3bh, w3bl);
    wsp(w3c, 512, 1024, w3ch, w3cl);

    // ---- SA1: N=1024 -> M=512, r=0.2, K=32, MLP 6->64->64->128
    fps_kernel<1024><<<32, 64, 0, stream>>>(xyz, 512, fps1, nx1);
    ballquery_kernel<<<ceil_div(32*512, 256), 256, 0, stream>>>(
        xyz, nx1, gi1, 32, 1024, 512, 32, (float)(0.2*0.2));
    {
        const int rows = 32*512*32;                     // 524288
        int ch = (int)((bufcap / (64*2)) & ~(size_t)255);
        if (ch > rows) ch = rows;
        if (ch < 256) ch = 256;
        for (int r0 = 0; r0 < rows; r0 += ch) {
            int rc = rows - r0 < ch ? rows - r0 : ch;
            sa_l1_kernel<3, 64, 32><<<rc/64, 256, 0, stream>>>(
                xyz, points, nx1, gi1, w1a, b1a, Ah, Al, 1024, 512, r0);
            mfma_layer_kernel<64, 64, 4, 4, 0, 0><<<dim3(rc/256, 1), 256, 0, stream>>>(
                Ah, Al, w1bh, w1bl, b1b, Bh, Bl, nullptr, 0);
            mfma_layer_kernel<64, 128, 8, 4, 32, 2><<<dim3(rc/256, 1), 256, 0, stream>>>(
                Bh, Bl, w1ch, w1cl, b1c, nullptr, nullptr, f1, r0);
        }
    }

    // ---- SA2: N=512 -> M=128, r=0.4, K=64, MLP 131->128->128->256
    fps_kernel<512><<<32, 64, 0, stream>>>(nx1, 128, fps2, nx2);
    ballquery_kernel<<<ceil_div(32*128, 256), 256, 0, stream>>>(
        nx1, nx2, gi2, 32, 512, 128, 64, (float)(0.4*0.4));
    {
        const int rows = 32*128*64;                     // 262144
        int ch = (int)((bufcap / (128*2)) & ~(size_t)255);
        if (ch > rows) ch = rows;
        if (ch < 256) ch = 256;
        for (int r0 = 0; r0 < rows; r0 += ch) {
            int rc = rows - r0 < ch ? rows - r0 : ch;
            sa_l1_kernel<128, 128, 64><<<rc/64, 256, 0, stream>>>(
                nx1, f1, nx2, gi2, w2a, b2a, Ah, Al, 512, 128, r0);
            mfma_layer_kernel<128, 128, 8, 4, 0, 0><<<dim3(rc/256, 1), 256, 0, stream>>>(
                Ah, Al, w2bh, w2bl, b2b, Bh, Bl, nullptr, 0);
            mfma_layer_kernel<128, 256, 16, 4, 64, 2><<<dim3(rc/256, 1), 256, 0, stream>>>(
                Bh, Bl, w2ch, w2cl, b2c, nullptr, nullptr, f2, r0);
        }
    }

    // ---- SA3 (group_all): concat [4096,259] -> 259->256 (fp32 gemm) ->
    //      256->512 (mfma) -> 512->1024 (mfma) -> max over 128
    concat_kernel<<<ceil_div(4096*259, 256), 256, 0, stream>>>(nx2, f2, g3, 4096, 256);
    {
        dim3 g(ceil_div(256, 64), ceil_div(4096, 64));
        gemm_kernel<1,1><<<g, 256, 0, stream>>>(g3, w3a, b3a, h3a, 4096, 256, 259);
    }
    asplit_kernel<<<ceil_div(4096*256, 256), 256, 0, stream>>>(h3a, h3aH, h3aL, 4096*256);
    // 256->512: NTILE=2, MROW=2 -> grid (32, 16) = 512 blocks.
    mfma_layer_kernel<256, 512, 2, 2, 0, 0><<<dim3(4096/128, 512/32), 256, 0, stream>>>(
        h3aH, h3aL, w3bh, w3bl, b3b, h3bH, h3bL, nullptr, 0);
    // 512->1024: NTILE=4, MROW=1 -> grid (64, 16) = 1024 blocks.
    mfma_layer_kernel<512, 1024, 4, 1, 0, 1><<<dim3(4096/64, 1024/64), 256, 0, stream>>>(
        h3bH, h3bL, w3ch, w3cl, b3c, nullptr, nullptr, h3c, 0);
    rowmax_kernel<<<ceil_div(32*1024, 256), 256, 0, stream>>>(h3c, f3, 32, 128, 1024);

    // ---- FC head (fp32, thread-per-output latency-optimized)
    fc_kernel<1,0><<<ceil_div(32*512, 256), 256, 0, stream>>>(
        f3, lin1, nullptr, fc1, 32, 512, 1024);
    fc_kernel<1,0><<<ceil_div(32*256, 256), 256, 0, stream>>>(
        fc1, lin2, nullptr, fc2, 32, 256, 512);
    fc_kernel<0,1><<<ceil_div(32*40, 256), 256, 0, stream>>>(
        fc2, clsw, clsb, (float*)d_out, 32, 40, 256);
}

// Round 16
// 1261.964 us; speedup vs baseline: 1.9508x; 1.0621x over previous
//
#include <hip/hip_runtime.h>

#define DEVFN __device__ __forceinline__

static inline int ceil_div(int a, int b) { return (a + b - 1) / b; }

typedef __attribute__((ext_vector_type(8))) short         bf16x8;  // 8 bf16 = 4 VGPR
typedef __attribute__((ext_vector_type(4))) float         f32x4;
typedef __attribute__((ext_vector_type(8))) unsigned short u16x8;

DEVFN unsigned short f2bf(float x) {           // RNE float->bf16 (finite inputs)
    unsigned u = __float_as_uint(x);
    unsigned r = ((u >> 16) & 1u) + 0x7fffu;
    return (unsigned short)((u + r) >> 16);
}
DEVFN float bf2f(unsigned short h) { return __uint_as_float(((unsigned)h) << 16); }

// ---------------------------------------------------------------------------
// DPP-based 64-lane max reduction step for a packed double key.
// ---------------------------------------------------------------------------
template<int CTRL>
DEVFN double dpp_max_step(double v)
{
    int lo = __double2loint(v), hi = __double2hiint(v);
    int tlo = __builtin_amdgcn_update_dpp(lo, lo, CTRL, 0xF, 0xF, false);
    int thi = __builtin_amdgcn_update_dpp(hi, hi, CTRL, 0xF, 0xF, false);
    return fmax(v, __hiloint2double(thi, tlo));
}

// ---------------------------------------------------------------------------
// Farthest point sampling — SINGLE WAVE per batch, packed-key argmax with
// 6-step DPP max reduce (unchanged; 202 µs @ N=1024).
// ---------------------------------------------------------------------------
template<int N>
__global__ __launch_bounds__(64) void fps_kernel(const float* __restrict__ xyz, int M,
                                                 int* __restrict__ out_idx,
                                                 float* __restrict__ nxout)
{
    constexpr int PPL = N / 64;
    int b = blockIdx.x, lane = threadIdx.x;
    __shared__ float4 sp[N];
    const float* p = xyz + (size_t)b * N * 3;
    float px[PPL], py[PPL], pz[PPL], dd[PPL];
    unsigned lo[PPL];
    #pragma unroll
    for (int j = 0; j < PPL; ++j) {
        int idx = lane + 64 * j;
        px[j] = p[idx*3+0]; py[j] = p[idx*3+1]; pz[j] = p[idx*3+2];
        sp[idx] = make_float4(px[j], py[j], pz[j], 0.f);
        dd[j] = 1e10f;
        lo[j] = ~(unsigned)idx;
    }
    __syncthreads();
    int far = 0;
    for (int s = 0; s < M; ++s) {
        float4 c4 = sp[far];
        if (lane == 0) {
            out_idx[(size_t)b*M + s] = far;
            nxout[((size_t)b*M + s)*3 + 0] = c4.x;
            nxout[((size_t)b*M + s)*3 + 1] = c4.y;
            nxout[((size_t)b*M + s)*3 + 2] = c4.z;
        }
        double cand[PPL];
        #pragma unroll
        for (int j = 0; j < PPL; ++j) {
            float dx = __fsub_rn(px[j], c4.x);
            float dy = __fsub_rn(py[j], c4.y);
            float dz = __fsub_rn(pz[j], c4.z);
            float d  = __fadd_rn(__fadd_rn(__fmul_rn(dx,dx), __fmul_rn(dy,dy)),
                                 __fmul_rn(dz,dz));
            float nd = fminf(dd[j], d);
            dd[j] = nd;
            cand[j] = __hiloint2double(__float_as_int(nd), (int)lo[j]);
        }
        #pragma unroll
        for (int st = PPL/2; st > 0; st >>= 1)
            #pragma unroll
            for (int j = 0; j < PPL; ++j)
                if (j < st) cand[j] = fmax(cand[j], cand[j + st]);
        double v = cand[0];
        v = dpp_max_step<0xB1>(v);
        v = dpp_max_step<0x4E>(v);
        v = dpp_max_step<0x124>(v);
        v = dpp_max_step<0x128>(v);
        v = dpp_max_step<0x142>(v);
        v = dpp_max_step<0x143>(v);
        int wlo = __builtin_amdgcn_readlane(__double2loint(v), 63);
        far = (int)(~(unsigned)wlo);
    }
}

// ---------------------------------------------------------------------------
// Ball query (unchanged).
// ---------------------------------------------------------------------------
__global__ void ballquery_kernel(const float* __restrict__ xyz,
                                 const float* __restrict__ new_xyz,
                                 int* __restrict__ gi,
                                 int B, int N, int M, int K, float r2)
{
    int t = blockIdx.x * blockDim.x + threadIdx.x;
    if (t >= B * M) return;
    int b = t / M;
    const float* p = xyz + (size_t)b * N * 3;
    float cx = new_xyz[t*3+0], cy = new_xyz[t*3+1], cz = new_xyz[t*3+2];
    int* out = gi + (size_t)t * K;
    int cnt = 0, first = 0;
    bool havefirst = false;
    for (int i = 0; i < N; ++i) {
        float dx = __fsub_rn(p[i*3+0], cx);
        float dy = __fsub_rn(p[i*3+1], cy);
        float dz = __fsub_rn(p[i*3+2], cz);
        float d  = __fadd_rn(__fadd_rn(__fmul_rn(dx,dx), __fmul_rn(dy,dy)),
                             __fmul_rn(dz,dz));
        if (d <= r2) {
            if (!havefirst) { first = i; havefirst = true; }
            out[cnt++] = i;
            if (cnt == K) break;
        }
    }
    for (; cnt < K; ++cnt) out[cnt] = first;
}

DEVFN float f4_elem(const float4& v, int u) {
    return u == 0 ? v.x : u == 1 ? v.y : u == 2 ? v.z : v.w;
}

// ---------------------------------------------------------------------------
// Weight split+transpose prep: w [CItot][CO] fp32 -> wh/wl [CO][CIpad] bf16
// pair; source row = ci + ro (rows outside [0,CItot) -> 0). Handles padding
// (SA3 L1: 259->288) and row offset (SA2 L1 feats part: rows 3..130).
// ---------------------------------------------------------------------------
__global__ void wsplit_kernel(const float* __restrict__ w,
                              unsigned short* __restrict__ wh,
                              unsigned short* __restrict__ wl,
                              int CItot, int CO, int CIpad, int ro)
{
    int t = blockIdx.x * 256 + threadIdx.x;
    if (t >= CIpad * CO) return;
    int co = t / CIpad, ci = t % CIpad;
    int src = ci + ro;
    float v = (src < CItot) ? w[(size_t)src * CO + co] : 0.f;
    unsigned short h = f2bf(v);
    wh[t] = h;
    wl[t] = f2bf(v - bf2f(h));
}

// ---------------------------------------------------------------------------
// SA1 layer 1 (fused gather + centering), fp32 VALU, writing ROW-MAJOR
// split-bf16 activations for the MFMA layers (unchanged from R12).
// ---------------------------------------------------------------------------
template<int CF, int CO, int KPTS>
__global__ __launch_bounds__(256) void sa_l1_kernel(
    const float* __restrict__ xyz, const float* __restrict__ feats,
    const float* __restrict__ new_xyz, const int* __restrict__ gi,
    const float* __restrict__ w, const float* __restrict__ bias,
    unsigned short* __restrict__ oh, unsigned short* __restrict__ ol,
    int N, int M, int row0)
{
    constexpr int WCH = CO / 4;
    const int lane = threadIdx.x & 63;
    const int wv   = __builtin_amdgcn_readfirstlane(threadIdx.x >> 6);
    const int rl   = blockIdx.x * 64 + lane;
    const int row  = row0 + rl;
    const int cent = row / KPTS;
    const int b    = cent / M;
    const int idx  = gi[row];
    const float* pp  = xyz + ((size_t)b*N + idx)*3;
    const float* cc3 = new_xyz + (size_t)cent*3;
    float a0 = __fsub_rn(pp[0], cc3[0]);
    float a1 = __fsub_rn(pp[1], cc3[1]);
    float a2 = __fsub_rn(pp[2], cc3[2]);
    const float* frow = feats + ((size_t)b*N + idx)*CF;
    const float* wcol = w + wv*WCH;
    const float* bcol = bias + wv*WCH;
    float acc[WCH];
    #pragma unroll
    for (int j = 0; j < WCH; ++j) acc[j] = bcol[j];
    #pragma unroll
    for (int j = 0; j < WCH; ++j) acc[j] += a0 * wcol[0*CO + j];
    #pragma unroll
    for (int j = 0; j < WCH; ++j) acc[j] += a1 * wcol[1*CO + j];
    #pragma unroll
    for (int j = 0; j < WCH; ++j) acc[j] += a2 * wcol[2*CO + j];
    constexpr int CF4 = CF & ~3;
    #pragma unroll 2
    for (int cc = 0; cc < CF4; cc += 4) {
        float4 a4 = *(const float4*)(frow + cc);
        #pragma unroll
        for (int u = 0; u < 4; ++u) {
            float a = f4_elem(a4, u);
            #pragma unroll
            for (int j = 0; j < WCH; ++j)
                acc[j] += a * wcol[(size_t)(3 + cc + u)*CO + j];
        }
    }
    #pragma unroll
    for (int f = CF4; f < CF; ++f) {
        float a = frow[f];
        #pragma unroll
        for (int j = 0; j < WCH; ++j)
            acc[j] += a * wcol[(size_t)(3 + f)*CO + j];
    }
    #pragma unroll
    for (int j8 = 0; j8 < WCH; j8 += 8) {
        u16x8 hv, lv;
        #pragma unroll
        for (int u = 0; u < 8; ++u) {
            float v = fmaxf(acc[j8+u], 0.f);
            unsigned short h = f2bf(v);
            hv[u] = (unsigned short)h;
            lv[u] = f2bf(v - bf2f(h));
        }
        size_t o = (size_t)rl*CO + wv*WCH + j8;
        *(u16x8*)(&oh[o]) = hv;
        *(u16x8*)(&ol[o]) = lv;
    }
}

// ---------------------------------------------------------------------------
// MFMA layer with column tiling + MROW row-tiles per wave.
// OUTMODE: 0 = split-bf16 out, 1 = fp32 out, 2 = maxpool->fp32,
//          3 = maxpool->split-bf16.
// ---------------------------------------------------------------------------
template<int CI, int CO, int NTILE, int MROW, int KPTS, int OUTMODE>
__global__ __launch_bounds__(256) void mfma_layer_kernel(
    const unsigned short* __restrict__ ah, const unsigned short* __restrict__ al,
    const unsigned short* __restrict__ wh, const unsigned short* __restrict__ wl,
    const float* __restrict__ bias,
    unsigned short* __restrict__ oh, unsigned short* __restrict__ ol,
    float* __restrict__ ofp, int rowbase)
{
    constexpr int KT = CI / 32;
    static_assert(KT * MROW <= 18, "A-preload register budget");
    __shared__ float partial[4][OUTMODE >= 2 ? MROW : 1][OUTMODE >= 2 ? 16*NTILE : 1];
    const int wid  = threadIdx.x >> 6;
    const int lane = threadIdx.x & 63;
    const int m    = lane & 15;
    const int kg   = lane >> 4;
    const int blockrow = blockIdx.x * (64 * MROW);
    const int colbase  = blockIdx.y * (16 * NTILE);
    bf16x8 Ahf[MROW * KT], Alf[MROW * KT];
    #pragma unroll
    for (int t = 0; t < MROW; ++t) {
        const unsigned short* arh =
            ah + (size_t)(blockrow + t*64 + wid*16 + m) * CI + kg * 8;
        const unsigned short* arl =
            al + (size_t)(blockrow + t*64 + wid*16 + m) * CI + kg * 8;
        #pragma unroll
        for (int kt = 0; kt < KT; ++kt) {
            Ahf[t*KT + kt] = *(const bf16x8*)(arh + kt*32);
            Alf[t*KT + kt] = *(const bf16x8*)(arl + kt*32);
        }
    }
    #pragma unroll
    for (int nt = 0; nt < NTILE; ++nt) {
        f32x4 acc[MROW];
        #pragma unroll
        for (int t = 0; t < MROW; ++t) acc[t] = (f32x4){0.f, 0.f, 0.f, 0.f};
        const unsigned short* wbh = wh + (size_t)(colbase + nt*16 + m) * CI + kg * 8;
        const unsigned short* wbl = wl + (size_t)(colbase + nt*16 + m) * CI + kg * 8;
        #pragma unroll
        for (int kt = 0; kt < KT; ++kt) {
            bf16x8 Bh = *(const bf16x8*)(wbh + kt*32);
            bf16x8 Bl = *(const bf16x8*)(wbl + kt*32);
            #pragma unroll
            for (int t = 0; t < MROW; ++t) {
                acc[t] = __builtin_amdgcn_mfma_f32_16x16x32_bf16(Ahf[t*KT+kt], Bh, acc[t], 0, 0, 0);
                acc[t] = __builtin_amdgcn_mfma_f32_16x16x32_bf16(Ahf[t*KT+kt], Bl, acc[t], 0, 0, 0);
                acc[t] = __builtin_amdgcn_mfma_f32_16x16x32_bf16(Alf[t*KT+kt], Bh, acc[t], 0, 0, 0);
            }
        }
        int dcol = colbase + nt*16 + m;
        float bv = bias[dcol];
        #pragma unroll
        for (int t = 0; t < MROW; ++t) {
            float v[4];
            #pragma unroll
            for (int r = 0; r < 4; ++r) v[r] = fmaxf(acc[t][r] + bv, 0.f);
            if constexpr (OUTMODE == 0) {
                #pragma unroll
                for (int r = 0; r < 4; ++r) {
                    size_t o = (size_t)(blockrow + t*64 + wid*16 + kg*4 + r) * CO + dcol;
                    unsigned short h = f2bf(v[r]);
                    oh[o] = h;
                    ol[o] = f2bf(v[r] - bf2f(h));
                }
            } else if constexpr (OUTMODE == 1) {
                #pragma unroll
                for (int r = 0; r < 4; ++r)
                    ofp[(size_t)(blockrow + t*64 + wid*16 + kg*4 + r) * CO + dcol] = v[r];
            } else {
                float mx = fmaxf(fmaxf(v[0], v[1]), fmaxf(v[2], v[3]));
                mx = fmaxf(mx, __shfl_xor(mx, 16));
                mx = fmaxf(mx, __shfl_xor(mx, 32));
                if (lane < 16) partial[wid][t][nt*16 + m] = mx;
            }
        }
    }
    if constexpr (OUTMODE >= 2) {
        __syncthreads();
        for (int c = threadIdx.x; c < 16*NTILE; c += 256) {
            #pragma unroll
            for (int t = 0; t < MROW; ++t) {
                if constexpr (KPTS == 64) {
                    float mx = fmaxf(fmaxf(partial[0][t][c], partial[1][t][c]),
                                     fmaxf(partial[2][t][c], partial[3][t][c]));
                    int cent = (rowbase + blockrow) / 64 + t;
                    if constexpr (OUTMODE == 2) {
                        ofp[(size_t)cent*CO + colbase + c] = mx;
                    } else {
                        size_t o = (size_t)cent*CO + colbase + c;
                        unsigned short h = f2bf(mx);
                        oh[o] = h; ol[o] = f2bf(mx - bf2f(h));
                    }
                } else {               // KPTS == 32: each 16-row pair is a centroid half
                    int cent0 = (rowbase + blockrow) / 32 + t*2;
                    float v0 = fmaxf(partial[0][t][c], partial[1][t][c]);
                    float v1 = fmaxf(partial[2][t][c], partial[3][t][c]);
                    if constexpr (OUTMODE == 2) {
                        ofp[(size_t)cent0*CO + colbase + c]     = v0;
                        ofp[(size_t)(cent0+1)*CO + colbase + c] = v1;
                    } else {
                        size_t o0 = (size_t)cent0*CO + colbase + c;
                        size_t o1 = (size_t)(cent0+1)*CO + colbase + c;
                        unsigned short h0 = f2bf(v0), h1 = f2bf(v1);
                        oh[o0] = h0; ol[o0] = f2bf(v0 - bf2f(h0));
                        oh[o1] = h1; ol[o1] = f2bf(v1 - bf2f(h1));
                    }
                }
            }
        }
    }
}

// ---------------------------------------------------------------------------
// SA2 layer 1 as MFMA with per-lane GATHERED A rows (f1 split bf16) plus the
// 3-channel xyz part computed on the VALU in the epilogue.
// rows (chunk-local) = 64*MROW per block; CI = CO = 128.
// ---------------------------------------------------------------------------
template<int NTILE, int MROW>
__global__ __launch_bounds__(256) void mfma_sa2l1_kernel(
    const float* __restrict__ sxyz,      // nx1 [32*512][3]
    const float* __restrict__ cxyz,      // nx2 [32*128][3]
    const int* __restrict__ gi,          // gi2
    const unsigned short* __restrict__ f1h, const unsigned short* __restrict__ f1l,
    const float* __restrict__ w,         // w2a [131][128] fp32 (rows 0..2 used here)
    const unsigned short* __restrict__ wh, const unsigned short* __restrict__ wl,
    const float* __restrict__ bias,      // [128]
    unsigned short* __restrict__ oh, unsigned short* __restrict__ ol,
    int rowbase)
{
    constexpr int CI = 128, CO = 128, KT = 4, KPTS = 64, M = 128, N = 512;
    const int wid  = threadIdx.x >> 6;
    const int lane = threadIdx.x & 63;
    const int m    = lane & 15;
    const int kg   = lane >> 4;
    const int blockrow = blockIdx.x * (64 * MROW);
    const int colbase  = blockIdx.y * (16 * NTILE);
    // A fragments: gathered f1 rows (per-lane addresses)
    bf16x8 Ahf[MROW * KT], Alf[MROW * KT];
    #pragma unroll
    for (int t = 0; t < MROW; ++t) {
        int grow = rowbase + blockrow + t*64 + wid*16 + m;
        int cent = grow / KPTS;
        int b    = cent / M;
        int idx  = gi[grow];
        const unsigned short* arh = f1h + ((size_t)b*N + idx) * CI + kg * 8;
        const unsigned short* arl = f1l + ((size_t)b*N + idx) * CI + kg * 8;
        #pragma unroll
        for (int kt = 0; kt < KT; ++kt) {
            Ahf[t*KT + kt] = *(const bf16x8*)(arh + kt*32);
            Alf[t*KT + kt] = *(const bf16x8*)(arl + kt*32);
        }
    }
    // xyz deltas for the OUTPUT rows this lane owns (rows kg*4+r of each tile)
    float dx[MROW][4], dy[MROW][4], dz[MROW][4];
    #pragma unroll
    for (int t = 0; t < MROW; ++t)
        #pragma unroll
        for (int r = 0; r < 4; ++r) {
            int grow = rowbase + blockrow + t*64 + wid*16 + kg*4 + r;
            int cent = grow / KPTS;
            int b    = cent / M;
            int idx  = gi[grow];
            const float* pp = sxyz + ((size_t)b*N + idx)*3;
            const float* cc = cxyz + (size_t)cent*3;
            dx[t][r] = __fsub_rn(pp[0], cc[0]);
            dy[t][r] = __fsub_rn(pp[1], cc[1]);
            dz[t][r] = __fsub_rn(pp[2], cc[2]);
        }
    #pragma unroll
    for (int nt = 0; nt < NTILE; ++nt) {
        f32x4 acc[MROW];
        #pragma unroll
        for (int t = 0; t < MROW; ++t) acc[t] = (f32x4){0.f, 0.f, 0.f, 0.f};
        const unsigned short* wbh = wh + (size_t)(colbase + nt*16 + m) * CI + kg * 8;
        const unsigned short* wbl = wl + (size_t)(colbase + nt*16 + m) * CI + kg * 8;
        #pragma unroll
        for (int kt = 0; kt < KT; ++kt) {
            bf16x8 Bh = *(const bf16x8*)(wbh + kt*32);
            bf16x8 Bl = *(const bf16x8*)(wbl + kt*32);
            #pragma unroll
            for (int t = 0; t < MROW; ++t) {
                acc[t] = __builtin_amdgcn_mfma_f32_16x16x32_bf16(Ahf[t*KT+kt], Bh, acc[t], 0, 0, 0);
                acc[t] = __builtin_amdgcn_mfma_f32_16x16x32_bf16(Ahf[t*KT+kt], Bl, acc[t], 0, 0, 0);
                acc[t] = __builtin_amdgcn_mfma_f32_16x16x32_bf16(Alf[t*KT+kt], Bh, acc[t], 0, 0, 0);
            }
        }
        int dcol = colbase + nt*16 + m;
        float w0 = w[0*CO + dcol], w1 = w[1*CO + dcol], w2 = w[2*CO + dcol];
        float bv = bias[dcol];
        #pragma unroll
        for (int t = 0; t < MROW; ++t)
            #pragma unroll
            for (int r = 0; r < 4; ++r) {
                float v = acc[t][r] + bv + dx[t][r]*w0 + dy[t][r]*w1 + dz[t][r]*w2;
                v = fmaxf(v, 0.f);
                size_t o = (size_t)(blockrow + t*64 + wid*16 + kg*4 + r) * CO + dcol;
                unsigned short h = f2bf(v);
                oh[o] = h;
                ol[o] = f2bf(v - bf2f(h));
            }
    }
}

// ---------------------------------------------------------------------------
// concat [R,3] ++ [R,CF] -> split-bf16 [R][CIpad] (zero padded).
// ---------------------------------------------------------------------------
__global__ void concat_split_kernel(const float* __restrict__ a, const float* __restrict__ f,
                                    unsigned short* __restrict__ oh,
                                    unsigned short* __restrict__ ol,
                                    int R, int CF, int CIpad)
{
    int t = blockIdx.x * 256 + threadIdx.x;
    if (t >= R * CIpad) return;
    int r = t / CIpad, c = t % CIpad;
    float v;
    if (c < 3) v = a[r*3 + c];
    else if (c < CF + 3) v = f[(size_t)r * CF + (c - 3)];
    else v = 0.f;
    unsigned short h = f2bf(v);
    oh[t] = h;
    ol[t] = f2bf(v - bf2f(h));
}

// ---------------------------------------------------------------------------
// Small-M FC GEMM: one thread per output element, no LDS, no barriers.
// ---------------------------------------------------------------------------
template<int RELU, int HASB>
__global__ __launch_bounds__(256) void fc_kernel(
    const float* __restrict__ A, const float* __restrict__ W,
    const float* __restrict__ bias, float* __restrict__ Cc,
    int Mr, int Nc, int Kd)
{
    int t = blockIdx.x * 256 + threadIdx.x;
    if (t >= Mr * Nc) return;
    int row = t / Nc, col = t % Nc;
    const float* a = A + (size_t)row * Kd;
    const float* w = W + col;
    float acc = 0.f;
    #pragma unroll 8
    for (int k = 0; k < Kd; ++k)
        acc += a[k] * w[(size_t)k * Nc];
    if (HASB) acc += bias[col];
    if (RELU) acc = fmaxf(acc, 0.f);
    Cc[t] = acc;
}

// ---------------------------------------------------------------------------
// Max over P points: in [B,P,C] -> out [B,C]
// ---------------------------------------------------------------------------
__global__ void rowmax_kernel(const float* __restrict__ in, float* __restrict__ out,
                              int B, int P, int C)
{
    int t = blockIdx.x * blockDim.x + threadIdx.x;
    if (t >= B * C) return;
    int b = t / C, c = t % C;
    const float* p = in + (size_t)b * P * C + c;
    float mx = p[0];
    for (int i = 1; i < P; ++i) mx = fmaxf(mx, p[(size_t)i * C]);
    out[t] = mx;
}

// ---------------------------------------------------------------------------
extern "C" void kernel_launch(void* const* d_in, const int* in_sizes, int n_in,
                              void* d_out, int out_size, void* d_ws, size_t ws_size,
                              hipStream_t stream)
{
    const float* xyz    = (const float*)d_in[0];
    const float* points = (const float*)d_in[1];
    const float* w1a = (const float*)d_in[2];  const float* b1a = (const float*)d_in[3];
    const float* w1b = (const float*)d_in[4];  const float* b1b = (const float*)d_in[5];
    const float* w1c = (const float*)d_in[6];  const float* b1c = (const float*)d_in[7];
    const float* w2a = (const float*)d_in[8];  const float* b2a = (const float*)d_in[9];
    const float* w2b = (const float*)d_in[10]; const float* b2b = (const float*)d_in[11];
    const float* w2c = (const float*)d_in[12]; const float* b2c = (const float*)d_in[13];
    const float* w3a = (const float*)d_in[14]; const float* b3a = (const float*)d_in[15];
    const float* w3b = (const float*)d_in[16]; const float* b3b = (const float*)d_in[17];
    const float* w3c = (const float*)d_in[18]; const float* b3c = (const float*)d_in[19];
    const float* lin1 = (const float*)d_in[20];
    const float* lin2 = (const float*)d_in[21];
    const float* clsw = (const float*)d_in[22];
    const float* clsb = (const float*)d_in[23];

    char* ws = (char*)d_ws;
    size_t off = 0;
    auto alloc = [&](size_t bytes) -> void* {
        void* p = ws + off;
        off += (bytes + 255) & ~(size_t)255;
        return p;
    };
    int*   fps1 = (int*)  alloc((size_t)32*512*4);
    float* nx1  = (float*)alloc((size_t)32*512*3*4);
    int*   gi1  = (int*)  alloc((size_t)32*512*32*4);
    int*   fps2 = (int*)  alloc((size_t)32*128*4);
    float* nx2  = (float*)alloc((size_t)32*128*3*4);
    int*   gi2  = (int*)  alloc((size_t)32*128*64*4);
    float* f2   = (float*)alloc((size_t)32*128*256*4);
    float* h3c  = (float*)alloc((size_t)4096*1024*4);
    float* f3   = (float*)alloc((size_t)32*1024*4);
    float* fc1  = (float*)alloc((size_t)32*512*4);
    float* fc2  = (float*)alloc((size_t)32*256*4);

    typedef unsigned short us;
    // split weights (transposed [CO][CIpad], bf16 hi/lo)
    us* w1bh = (us*)alloc(64*64*2);     us* w1bl = (us*)alloc(64*64*2);
    us* w1ch = (us*)alloc(128*64*2);    us* w1cl = (us*)alloc(128*64*2);
    us* w2ah = (us*)alloc(128*128*2);   us* w2al = (us*)alloc(128*128*2);   // feats part (rows 3..130)
    us* w2bh = (us*)alloc(128*128*2);   us* w2bl = (us*)alloc(128*128*2);
    us* w2ch = (us*)alloc(256*128*2);   us* w2cl = (us*)alloc(256*128*2);
    us* w3ah = (us*)alloc(256*288*2);   us* w3al = (us*)alloc(256*288*2);   // padded 259->288
    us* w3bh = (us*)alloc(512*256*2);   us* w3bl = (us*)alloc(512*256*2);
    us* w3ch = (us*)alloc(1024*512*2);  us* w3cl = (us*)alloc(1024*512*2);
    // SA1 output (split) = SA2 input feats
    us* f1h  = (us*)alloc((size_t)16384*128*2);
    us* f1l  = (us*)alloc((size_t)16384*128*2);
    // SA3 activations
    us* g3H  = (us*)alloc((size_t)4096*288*2);  us* g3L  = (us*)alloc((size_t)4096*288*2);
    us* h3aH = (us*)alloc((size_t)4096*256*2);  us* h3aL = (us*)alloc((size_t)4096*256*2);
    us* h3bH = (us*)alloc((size_t)4096*512*2);  us* h3bL = (us*)alloc((size_t)4096*512*2);

    // big split activation ping-pong buffers (hi/lo per side)
    size_t avail = (ws_size > off + 1024) ? (ws_size - off - 1024) : 0;
    size_t bufcap = avail / 4;
    if (bufcap > (size_t)67200000) bufcap = 67200000;   // 524288 rows x 64ch x 2B
    us* Ah = (us*)alloc(bufcap); us* Al = (us*)alloc(bufcap);
    us* Bh = (us*)alloc(bufcap); us* Bl = (us*)alloc(bufcap);

    // ---- weight prep
    auto wsp = [&](const float* w, int CItot, int CO, int CIpad, int ro, us* wh, us* wl) {
        wsplit_kernel<<<ceil_div(CIpad*CO, 256), 256, 0, stream>>>(w, wh, wl, CItot, CO, CIpad, ro);
    };
    wsp(w1b, 64, 64, 64, 0,   w1bh, w1bl);
    wsp(w1c, 64, 128, 64, 0,  w1ch, w1cl);
    wsp(w2a, 131, 128, 128, 3, w2ah, w2al);
    wsp(w2b, 128, 128, 128, 0, w2bh, w2bl);
    wsp(w2c, 128, 256, 128, 0, w2ch, w2cl);
    wsp(w3a, 259, 256, 288, 0, w3ah, w3al);
    wsp(w3b, 256, 512, 256, 0, w3bh, w3bl);
    wsp(w3c, 512, 1024, 512, 0, w3ch, w3cl);

    // ---- SA1: N=1024 -> M=512, r=0.2, K=32, MLP 6->64->64->128
    fps_kernel<1024><<<32, 64, 0, stream>>>(xyz, 512, fps1, nx1);
    ballquery_kernel<<<ceil_div(32*512, 256), 256, 0, stream>>>(
        xyz, nx1, gi1, 32, 1024, 512, 32, (float)(0.2*0.2));
    {
        const int rows = 32*512*32;                     // 524288
        int ch = (int)((bufcap / (64*2)) & ~(size_t)1023);
        if (ch > rows) ch = rows;
        if (ch < 1024) ch = 1024;
        for (int r0 = 0; r0 < rows; r0 += ch) {
            int rc = rows - r0 < ch ? rows - r0 : ch;
            sa_l1_kernel<3, 64, 32><<<rc/64, 256, 0, stream>>>(
                xyz, points, nx1, gi1, w1a, b1a, Ah, Al, 1024, 512, r0);
            mfma_layer_kernel<64, 64, 4, 4, 0, 0><<<dim3(rc/256, 1), 256, 0, stream>>>(
                Ah, Al, w1bh, w1bl, b1b, Bh, Bl, nullptr, 0);
            mfma_layer_kernel<64, 128, 8, 4, 32, 3><<<dim3(rc/256, 1), 256, 0, stream>>>(
                Bh, Bl, w1ch, w1cl, b1c, f1h, f1l, nullptr, r0);
        }
    }

    // ---- SA2: N=512 -> M=128, r=0.4, K=64, MLP 131->128->128->256
    fps_kernel<512><<<32, 64, 0, stream>>>(nx1, 128, fps2, nx2);
    ballquery_kernel<<<ceil_div(32*128, 256), 256, 0, stream>>>(
        nx1, nx2, gi2, 32, 512, 128, 64, (float)(0.4*0.4));
    {
        const int rows = 32*128*64;                     // 262144
        int ch = (int)((bufcap / (128*2)) & ~(size_t)1023);
        if (ch > rows) ch = rows;
        if (ch < 1024) ch = 1024;
        for (int r0 = 0; r0 < rows; r0 += ch) {
            int rc = rows - r0 < ch ? rows - r0 : ch;
            // L1: MFMA over gathered f1 rows + VALU xyz part -> Ah/Al
            mfma_sa2l1_kernel<8, 2><<<dim3(rc/128, 1), 256, 0, stream>>>(
                nx1, nx2, gi2, f1h, f1l, w2a, w2ah, w2al, b2a, Ah, Al, r0);
            mfma_layer_kernel<128, 128, 8, 4, 0, 0><<<dim3(rc/256, 1), 256, 0, stream>>>(
                Ah, Al, w2bh, w2bl, b2b, Bh, Bl, nullptr, 0);
            mfma_layer_kernel<128, 256, 16, 4, 64, 2><<<dim3(rc/256, 1), 256, 0, stream>>>(
                Bh, Bl, w2ch, w2cl, b2c, nullptr, nullptr, f2, r0);
        }
    }

    // ---- SA3 (group_all): concat-split [4096][288] -> 288->256 (mfma) ->
    //      256->512 (mfma) -> 512->1024 (mfma) -> max over 128
    concat_split_kernel<<<ceil_div(4096*288, 256), 256, 0, stream>>>(
        nx2, f2, g3H, g3L, 4096, 256, 288);
    // 288->256: KT=9, NTILE=2, MROW=1 -> grid (64, 8) = 512 blocks.
    mfma_layer_kernel<288, 256, 2, 1, 0, 0><<<dim3(4096/64, 256/32), 256, 0, stream>>>(
        g3H, g3L, w3ah, w3al, b3a, h3aH, h3aL, nullptr, 0);
    // 256->512: NTILE=2, MROW=2 -> grid (32, 16) = 512 blocks.
    mfma_layer_kernel<256, 512, 2, 2, 0, 0><<<dim3(4096/128, 512/32), 256, 0, stream>>>(
        h3aH, h3aL, w3bh, w3bl, b3b, h3bH, h3bL, nullptr, 0);
    // 512->1024: NTILE=4, MROW=1 -> grid (64, 16) = 1024 blocks.
    mfma_layer_kernel<512, 1024, 4, 1, 0, 1><<<dim3(4096/64, 1024/64), 256, 0, stream>>>(
        h3bH, h3bL, w3ch, w3cl, b3c, nullptr, nullptr, h3c, 0);
    rowmax_kernel<<<ceil_div(32*1024, 256), 256, 0, stream>>>(h3c, f3, 32, 128, 1024);

    // ---- FC head (fp32, thread-per-output latency-optimized)
    fc_kernel<1,0><<<ceil_div(32*512, 256), 256, 0, stream>>>(
        f3, lin1, nullptr, fc1, 32, 512, 1024);
    fc_kernel<1,0><<<ceil_div(32*256, 256), 256, 0, stream>>>(
        fc1, lin2, nullptr, fc2, 32, 256, 512);
    fc_kernel<0,1><<<ceil_div(32*40, 256), 256, 0, stream>>>(
        fc2, clsw, clsb, (float*)d_out, 32, 40, 256);
}